// Round 14
// baseline (1553.685 us; speedup 1.0000x reference)
//
#include <hip/hip_runtime.h>
#include <math.h>

typedef __bf16 bf16x8 __attribute__((ext_vector_type(8)));
typedef float  f32x16 __attribute__((ext_vector_type(16)));
typedef unsigned int u32x4 __attribute__((ext_vector_type(4)));

static __device__ __forceinline__ f32x16 MFMA(bf16x8 a, bf16x8 b, f32x16 c){
  return __builtin_amdgcn_mfma_f32_32x32x16_bf16(a, b, c, 0, 0, 0);
}
static __device__ __forceinline__ unsigned short f2bf(float x){
  unsigned int u = __builtin_bit_cast(unsigned int, x);
  u += 0x7fffu + ((u >> 16) & 1u);   // RNE
  return (unsigned short)(u >> 16);
}
static __device__ __forceinline__ unsigned int pack2(float a, float b){
  return ((unsigned int)f2bf(b) << 16) | (unsigned int)f2bf(a);
}
static __device__ __forceinline__ bf16x8 ldfrag(const unsigned short* p){
  return __builtin_bit_cast(bf16x8, *(const uint4*)p);
}
// C-layout row for 32x32x16: row = (reg&3) + 8*(reg>>2) + 4*(lane>>5)
static __device__ __forceinline__ int rowmap(int reg, int lane){
  return (reg & 3) + 8 * (reg >> 2) + 4 * (lane >> 5);
}

// ------------------------------------------------ weight transpose+cast (once)
// in_w part: [col][384] as before (k_inproj unchanged).
// q/k/v parts: k-block-interleaved [k16][col][hi][8] so a GEMM wave's weight
// load is contiguous/coalesced.
__global__ __launch_bounds__(256) void k_wprep(const float* __restrict__ in_w,
    const float* __restrict__ q_w, const float* __restrict__ k_w,
    const float* __restrict__ v_w, unsigned short* __restrict__ wT){
  int idx = blockIdx.x * 256 + threadIdx.x;   // 983040 total
  float v;
  if (idx < 98304){
    int c = idx / 384, k = idx % 384;
    v = in_w[k * 256 + c];
  } else {
    int e = idx - 98304;
    int m = e / 73728, r = e % 73728;
    int k16 = r / 4096, rem = r % 4096;
    int c = rem / 16, kk = rem & 15;
    int k = k16 * 16 + kk;
    int p = m % 3, layer = m / 3;
    const float* src = (p == 0) ? q_w : (p == 1) ? k_w : v_w;
    v = src[(size_t)layer * 73728 + k * 256 + c];
  }
  wT[idx] = f2bf(v);
}

// ------------------------------------------------ temporal emb (bf16, masked)
__global__ __launch_bounds__(256) void k_temporal(const float* __restrict__ tim,
                                                  unsigned int* __restrict__ tem){
  int idx = blockIdx.x * 256 + threadIdx.x;   // 65536*16
  int i = idx & 15, m = idx >> 4;
  float t = tim[m];
  float np = (t > 0.0f) ? 1.0f : 0.0f;
  float dv = expf((float)(2 * i) * (-0.28782313662425576f));
  float arg = t * dv;
  tem[m * 16 + i] = pack2(sinf(arg) * np, cosf(arg) * np);
}

// ------------------------------------------------ input projection (MFMA)
__global__ __launch_bounds__(256, 2) void k_inproj(const int* __restrict__ subj,
    const int* __restrict__ obj, const int* __restrict__ rel,
    const float* __restrict__ ent, const float* __restrict__ rele,
    const unsigned short* __restrict__ inwT, const float* __restrict__ in_b,
    unsigned short* __restrict__ enc){
  __shared__ __align__(16) unsigned short A[64 * 392];  // reused as SB[64*264] after
  int t = threadIdx.x;
  int m0 = blockIdx.x * 64;
  { // gather 64 rows of concat(ent[s],ent[o],rel[r]) as bf16
    int r = t >> 2, c = t & 3;
    int m = m0 + r;
    const float4* s0 = (const float4*)(ent  + (size_t)subj[m] * 128 + c * 32);
    const float4* s1 = (const float4*)(ent  + (size_t)obj[m]  * 128 + c * 32);
    const float4* s2 = (const float4*)(rele + (size_t)rel[m]  * 128 + c * 32);
    unsigned int* dst = (unsigned int*)&A[r * 392];
#pragma unroll
    for (int j = 0; j < 8; j++){
      float4 f0 = s0[j], f1 = s1[j], f2 = s2[j];
      dst[c * 16 + 2 * j]           = pack2(f0.x, f0.y);
      dst[c * 16 + 2 * j + 1]       = pack2(f0.z, f0.w);
      dst[64 + c * 16 + 2 * j]      = pack2(f1.x, f1.y);
      dst[64 + c * 16 + 2 * j + 1]  = pack2(f1.z, f1.w);
      dst[128 + c * 16 + 2 * j]     = pack2(f2.x, f2.y);
      dst[128 + c * 16 + 2 * j + 1] = pack2(f2.z, f2.w);
    }
  }
  __syncthreads();
  int w = t >> 6, lane = t & 63;
  int lrow = lane & 31, khalf = (lane >> 5) * 8;
  int colA = (w * 2) * 32 + lrow, colB = colA + 32;
  f32x16 acc[2][2] = {};
  bf16x8 pb0 = ldfrag(&inwT[(size_t)colA * 384 + khalf]);
  bf16x8 pb1 = ldfrag(&inwT[(size_t)colB * 384 + khalf]);
  for (int ks = 0; ks < 24; ks++){
    int koff = ks * 16 + khalf;
    bf16x8 a0 = ldfrag(&A[lrow * 392 + koff]);
    bf16x8 a1 = ldfrag(&A[(32 + lrow) * 392 + koff]);
    bf16x8 b0 = pb0, b1 = pb1;
    if (ks < 23){
      pb0 = ldfrag(&inwT[(size_t)colA * 384 + koff + 16]);
      pb1 = ldfrag(&inwT[(size_t)colB * 384 + koff + 16]);
    }
    acc[0][0] = MFMA(a0, b0, acc[0][0]);
    acc[1][0] = MFMA(a1, b0, acc[1][0]);
    acc[0][1] = MFMA(a0, b1, acc[0][1]);
    acc[1][1] = MFMA(a1, b1, acc[1][1]);
  }
  float bs0 = in_b[colA], bs1 = in_b[colB];
  __syncthreads();            // A dead; reuse as SB[64][264]
#pragma unroll
  for (int rt = 0; rt < 2; rt++)
#pragma unroll
    for (int reg = 0; reg < 16; reg++){
      int row = rt * 32 + rowmap(reg, lane);
      A[row * 264 + colA] = f2bf(acc[rt][0][reg] + bs0);
      A[row * 264 + colB] = f2bf(acc[rt][1][reg] + bs1);
    }
  __syncthreads();
  {
    int r = t >> 2, s = t & 3;
    const uint4* src = (const uint4*)&A[r * 264 + s * 64];
    uint4* dst = (uint4*)(enc + ((size_t)m0 + r) * 256 + s * 64);
#pragma unroll
    for (int j = 0; j < 8; j++) dst[j] = src[j];
  }
}

// ------------------------------------------------ fused QKV projection + attention (v2)
// One block per sequence, 8 waves. GEMM phase: 8 chunks of 32 ci rows; per
// chunk ONE interleaved Q/K/V pass (acc 48 regs, ILP-3, coalesced k-block
// weights). K -> KV LDS directly (swizzled); Q -> per-wave qf regs via PAD;
// V -> global vtb (scatter; L2-resident, re-read as vst). Attention phase =
// R12 k_attn verbatim. NOTE: vtb must be 512 blocks x 128 KB = 67 MB.
__global__ __launch_bounds__(512, 2) void k_fused2(
    unsigned short* __restrict__ enc, float* __restrict__ cur,
    const unsigned short* __restrict__ tem,
    const unsigned short* __restrict__ wq, const unsigned short* __restrict__ wk,
    const unsigned short* __restrict__ wv,
    const float* __restrict__ bq, const float* __restrict__ bk,
    const float* __restrict__ bv,
    unsigned short* __restrict__ vtb, const float* __restrict__ tim, int lzero){
  __shared__ __align__(16) unsigned short KV[65536];  // 131072 B: [256 keys][512 B], byte ^= (key&7)<<4
  __shared__ __align__(16) unsigned short PAD[9216];  // 18432 B: CI[32 rows][576 B] <-> QP[32][264]
  __shared__ float TS[128];
  char* KVb = (char*)KV;
  char* PADb = (char*)PAD;
  int t = threadIdx.x;
  int nn = blockIdx.x;
  int w = t >> 6, lane = t & 63;
  int lrow = lane & 31, hi = lane >> 5;
  int hi4 = hi * 4, khalf = hi * 8;
  int col = w * 32 + lrow;     // GEMM output column / attention q
  int q = col;

  if (t < 128) TS[t] = tim[(size_t)nn * 128 + t];
  float bqv = bq[col], bkv = bk[col], bvv = bv[col];
  int aswz = (lrow & 7) << 4;
  const char* a0p = PADb + lrow * 576;
  unsigned short* vt = vtb + (size_t)nn * 65536;
  bf16x8 qf[16];

  // ================= GEMM phase: 8 chunks of 32 ci rows =================
#pragma unroll 1
  for (int c = 0; c < 8; c++){
    { // stage CI chunk c -> PAD as swizzled [32][576 B] (incl. tem cols)
      int r = t >> 4, sub = t & 15;
      int grow = c * 32 + r;
      int swz = (r & 7) << 4;
      char* dst = PADb + r * 576;
      if (grow < 128){
        const uint4* s4 = (const uint4*)(enc + ((size_t)nn * 128 + grow) * 256 + sub * 16);
        uint4 u0 = s4[0], u1 = s4[1];
        *(uint4*)(dst + ((sub * 32) ^ swz)) = u0;
        *(uint4*)(dst + ((sub * 32 + 16) ^ swz)) = u1;
      } else if (!lzero){
        const float4* s4 = (const float4*)(cur + ((size_t)nn * 128 + grow - 128) * 256 + sub * 16);
        float4 f0 = s4[0], f1 = s4[1], f2 = s4[2], f3 = s4[3];
        *(uint4*)(dst + ((sub * 32) ^ swz)) =
            make_uint4(pack2(f0.x, f0.y), pack2(f0.z, f0.w), pack2(f1.x, f1.y), pack2(f1.z, f1.w));
        *(uint4*)(dst + ((sub * 32 + 16) ^ swz)) =
            make_uint4(pack2(f2.x, f2.y), pack2(f2.z, f2.w), pack2(f3.x, f3.y), pack2(f3.z, f3.w));
      } else {
        uint4 z = make_uint4(0, 0, 0, 0);
        *(uint4*)(dst + ((sub * 32) ^ swz)) = z;
        *(uint4*)(dst + ((sub * 32 + 16) ^ swz)) = z;
      }
      if (sub < 4){
        int jr = grow & 127;
        *(uint4*)(dst + 512 + ((sub * 16) ^ (swz & 48))) =
            *(const uint4*)(tem + ((size_t)nn * 128 + jr) * 32 + sub * 8);
      }
    }
    __syncthreads();                                   // (A) CI ready

    // ---- interleaved Q/K/V GEMM: 32 rows x 256 cols, K=288 ----
    f32x16 accQ = {}, accK = {}, accV = {};
    {
      bf16x8 pq = ldfrag(&wq[col * 16 + khalf]);
      bf16x8 pk = ldfrag(&wk[col * 16 + khalf]);
      bf16x8 pv = ldfrag(&wv[col * 16 + khalf]);
#pragma unroll
      for (int ks = 0; ks < 18; ks++){
        bf16x8 a;
        if (ks < 16)
          a = ldfrag((const unsigned short*)(a0p + ((ks * 32 + hi * 16) ^ aswz)));
        else {
          int toff = (ks - 16) * 32 + hi * 16;
          a = ldfrag((const unsigned short*)(a0p + 512 + (toff ^ (aswz & 48))));
        }
        bf16x8 uq = pq, uk = pk, uv = pv;
        if (ks < 17){
          int kbase = (ks + 1) * 4096;
          pq = ldfrag(&wq[kbase + col * 16 + khalf]);
          pk = ldfrag(&wk[kbase + col * 16 + khalf]);
          pv = ldfrag(&wv[kbase + col * 16 + khalf]);
        }
        accQ = MFMA(a, uq, accQ);
        accK = MFMA(a, uk, accK);
        accV = MFMA(a, uv, accV);
      }
    }
    // K -> KV swizzled (attention home); V -> vtb (global, L2-resident)
#pragma unroll
    for (int reg = 0; reg < 16; reg++){
      int kl = rowmap(reg, lane);
      int key = c * 32 + kl;
      *(unsigned short*)(KVb + key * 512 + ((col * 2) ^ ((key & 7) << 4))) =
          f2bf(accK[reg] + bkv);
      vt[(size_t)col * 256 + key] = f2bf(accV[reg] + bvv);
    }
    __syncthreads();                                   // (B) CI consumed
    // Q -> QP (over CI region)
#pragma unroll
    for (int reg = 0; reg < 16; reg++){
      int rl = rowmap(reg, lane);
      PAD[rl * 264 + col] = f2bf(accQ[reg] + bqv);
    }
    __syncthreads();                                   // (C) QP ready
    if (w == c){
#pragma unroll
      for (int ks2 = 0; ks2 < 16; ks2++)
        qf[ks2] = ldfrag(&PAD[lrow * 264 + ks2 * 16 + khalf]);
    }
    __syncthreads();                                   // (D) QP consumed
  }

  // ================= attention phase (R12 k_attn verbatim) =================
  // ---- issue V^T loads early (written to LDS after QK phase) ----
  uint4 vst[16];
#pragma unroll
  for (int it = 0; it < 16; it++){
    int row = w * 32 + it * 2 + hi;
    vst[it] = *(const uint4*)(vt + (size_t)row * 256 + lrow * 8);
  }

  // key-time==0 masks for keys 0..127 (lane-uniform words)
  unsigned long long mm0 = __ballot(TS[lane] == 0.0f);
  unsigned long long mm1 = __ballot(TS[lane + 64] == 0.0f);
  unsigned int tz32[4] = { (unsigned int)mm0, (unsigned int)(mm0 >> 32),
                           (unsigned int)mm1, (unsigned int)(mm1 >> 32) };

  bool top = (q < 128);
  int qcmp = q & 127;
  float sum = 0.0f;
  unsigned int pw[8][8];   // packed bf16 e-pairs per key-tile

  // ---- QK^T (swapped: C[row=key][col=q]) + mask + exp + pack, per tile ----
#pragma unroll
  for (int kt = 0; kt < 8; kt++){
    bool need = top ? (kt <= w) : ((kt <= w - 4) || (kt == w));   // wave-uniform
    if (need){
      f32x16 s = {};
#pragma unroll
      for (int ks = 0; ks < 16; ks++){
        int row = kt * 32 + lrow;
        bf16x8 a = ldfrag((const unsigned short*)(KVb + row * 512 +
                          ((ks * 32 + hi * 16) ^ ((row & 7) << 4))));
        s = MFMA(a, qf[ks], s);
      }
#pragma unroll
      for (int j = 0; j < 8; j++){
        float e2[2];
#pragma unroll
        for (int u = 0; u < 2; u++){
          int r = 2 * j + u;
          int pat = (r & 3) + 8 * (r >> 2);
          int key = kt * 32 + pat + hi4;
          float sv = s[r] * 0.0625f;
          bool masked;
          if (kt < 4){
            bool tzb = (tz32[kt] >> (pat + hi4)) & 1;
            masked = (key >= qcmp) || tzb;
          } else {
            masked = top || (key != q);
          }
          float e = masked ? 0.0f : __expf(sv);
          sum += e;
          e2[u] = e;
        }
        pw[kt][j] = pack2(e2[0], e2[1]);
      }
    }
  }
  sum += __shfl_xor(sum, 32, 64);
  float rs = (sum > 0.0f) ? 1.0f / sum : 0.0f;
  bool am = (sum == 0.0f);   // all-masked row -> uniform 1/256 over ALL keys

  // ---- swap buffer to V^T[d][key] ----
  __syncthreads();           // all K reads done
#pragma unroll
  for (int it = 0; it < 16; it++){
    int row = w * 32 + it * 2 + hi;
    *(uint4*)(KVb + row * 512 + ((lrow * 16) ^ ((row & 7) << 4))) = vst[it];
  }
  __syncthreads();

  // ---- PV: O^T[d][q] += V^T-frag x P-frag, masked tiles skipped ----
  f32x16 ov[8] = {};
#pragma unroll
  for (int kt = 0; kt < 8; kt++){
    bool need = top ? (kt <= w) : ((kt <= w - 4) || (kt == w));
    if (need){
      unsigned int s0 = __shfl_xor(pw[kt][0], 32, 64);
      unsigned int s1 = __shfl_xor(pw[kt][1], 32, 64);
      unsigned int s2 = __shfl_xor(pw[kt][2], 32, 64);
      unsigned int s3 = __shfl_xor(pw[kt][3], 32, 64);
      unsigned int s4 = __shfl_xor(pw[kt][4], 32, 64);
      unsigned int s5 = __shfl_xor(pw[kt][5], 32, 64);
      unsigned int s6 = __shfl_xor(pw[kt][6], 32, 64);
      unsigned int s7 = __shfl_xor(pw[kt][7], 32, 64);
      u32x4 fe = { hi ? s2 : pw[kt][0], hi ? s3 : pw[kt][1],
                   hi ? pw[kt][2] : s0, hi ? pw[kt][3] : s1 };
      u32x4 fo = { hi ? s6 : pw[kt][4], hi ? s7 : pw[kt][5],
                   hi ? pw[kt][6] : s4, hi ? pw[kt][7] : s5 };
      bf16x8 be = __builtin_bit_cast(bf16x8, fe);
      bf16x8 bo = __builtin_bit_cast(bf16x8, fo);
#pragma unroll
      for (int dt = 0; dt < 8; dt++){
        int row = dt * 32 + lrow;
        int swz = (row & 7) << 4;
        bf16x8 a0 = ldfrag((const unsigned short*)(KVb + row * 512 + ((kt * 64 + hi * 16) ^ swz)));
        bf16x8 a1 = ldfrag((const unsigned short*)(KVb + row * 512 + ((kt * 64 + 32 + hi * 16) ^ swz)));
        ov[dt] = MFMA(a0, be, ov[dt]);
        ov[dt] = MFMA(a1, bo, ov[dt]);
      }
    }
  }
  // normalize (deferred); am lanes get zero then the uniform pass below
#pragma unroll
  for (int dt = 0; dt < 8; dt++)
#pragma unroll
    for (int r = 0; r < 16; r++) ov[dt][r] *= rs;

  if (__ballot(am)){   // rare: wave 0 (q=0) structurally; lane-predicated uniform P
    float cc = am ? 0.00390625f : 0.0f;
    unsigned int uwd = pack2(cc, cc);
    u32x4 fu = { uwd, uwd, uwd, uwd };
    bf16x8 bu = __builtin_bit_cast(bf16x8, fu);
#pragma unroll
    for (int s2i = 0; s2i < 16; s2i++){
#pragma unroll
      for (int dt = 0; dt < 8; dt++){
        int row = dt * 32 + lrow;
        bf16x8 a = ldfrag((const unsigned short*)(KVb + row * 512 +
                          ((s2i * 32 + hi * 16) ^ ((row & 7) << 4))));
        ov[dt] = MFMA(a, bu, ov[dt]);
      }
    }
  }

  // ---- epilogue: enc (q<128, bf16) then cur (q>=128, f32 tanh accumulate) ----
  __syncthreads();           // V^T reads done; KV reused for O staging
  if (w < 4){                // bf16 O[q][d], swizzled, lower 64 KB
#pragma unroll
    for (int dt = 0; dt < 8; dt++)
#pragma unroll
      for (int j = 0; j < 8; j++){
        int r = 2 * j;
        int pat = (r & 3) + 8 * (r >> 2);
        int d = dt * 32 + pat + hi4;
        *(unsigned int*)(KVb + q * 512 + ((d * 2) ^ ((q & 7) << 4))) =
            pack2(ov[dt][r], ov[dt][r + 1]);
      }
  }
  __syncthreads();
  {                          // coalesced store of enc
    int row = t >> 2;
    const char* src = KVb + row * 512;
    unsigned short* dst = enc + ((size_t)nn * 128 + row) * 256;
    int swz = (row & 7) << 4;
#pragma unroll
    for (int jj = 0; jj < 8; jj++){
      int cc = jj * 4 + (t & 3);
      uint4 v = *(const uint4*)(src + ((cc * 16) ^ swz));
      *(uint4*)(dst + cc * 8) = v;
    }
  }
  __syncthreads();
  if (w >= 4){               // f32 tanh values [qq][d], swizzled, full 128 KB
    int qq = q - 128;
    float tq = TS[qq];
#pragma unroll
    for (int dt = 0; dt < 8; dt++)
#pragma unroll
      for (int j = 0; j < 8; j++){
        int r = 2 * j;
        int pat = (r & 3) + 8 * (r >> 2);
        int d = dt * 32 + pat + hi4;
        float th0 = 0.0f, th1 = 0.0f;
        if (tq > 0.0f){
          th0 = 1.0f - 2.0f / (__expf(2.0f * ov[dt][r]) + 1.0f);
          th1 = 1.0f - 2.0f / (__expf(2.0f * ov[dt][r + 1]) + 1.0f);
        }
        float2 p2 = make_float2(th0, th1);
        *(float2*)(KVb + qq * 1024 + ((d * 4) ^ ((qq & 7) << 4))) = p2;
      }
  }
  __syncthreads();
  {                          // coalesced cur update (RMW unless lzero)
    int row = t >> 2;
    int swz = (row & 7) << 4;
    const char* src = KVb + row * 1024;
    float* dst = cur + ((size_t)nn * 128 + row) * 256;
#pragma unroll
    for (int jj = 0; jj < 16; jj++){
      int cc = jj * 4 + (t & 3);
      float4 v = *(const float4*)(src + ((cc * 16) ^ swz));
      if (!lzero){
        float4 o = *(const float4*)(dst + cc * 4);
        v.x += o.x; v.y += o.y; v.z += o.z; v.w += o.w;
      }
      *(float4*)(dst + cc * 4) = v;
    }
  }
}

// ------------------------------------------------ save feat (cur at j=L-1)
__global__ __launch_bounds__(256) void k_savefeat(const float* __restrict__ cur,
                                                  float* __restrict__ feat, int h){
  int idx = blockIdx.x * 256 + threadIdx.x;   // 512*256
  int n = idx >> 8, c = idx & 255;
  feat[(size_t)n * 512 + h * 256 + c] = cur[((size_t)n * 128 + 127) * 256 + c];
}

// ------------------------------------------------ output MLP head
__global__ __launch_bounds__(256) void k_mlp(const float* __restrict__ feat,
    const float* __restrict__ w1, const float* __restrict__ b1,
    const float* __restrict__ w2, const float* __restrict__ b2,
    float* __restrict__ out){
  __shared__ float F[512];
  __shared__ float red[4];
  int n = blockIdx.x, t = threadIdx.x;
  F[t]       = feat[(size_t)n * 512 + t];
  F[t + 256] = feat[(size_t)n * 512 + 256 + t];
  __syncthreads();
  float acc = 0.0f;
  for (int k4 = 0; k4 < 128; k4++){
    float b0v = w1[(k4 * 4 + 0) * 256 + t];
    float b1v = w1[(k4 * 4 + 1) * 256 + t];
    float b2v = w1[(k4 * 4 + 2) * 256 + t];
    float b3v = w1[(k4 * 4 + 3) * 256 + t];
    const float4 f = *(const float4*)&F[k4 * 4];
    acc = fmaf(f.x, b0v, fmaf(f.y, b1v, fmaf(f.z, b2v, fmaf(f.w, b3v, acc))));
  }
  acc += b1[t];
  float g = 0.5f * acc * (1.0f + erff(acc * 0.7071067811865475f));
  float part = g * w2[t];
#pragma unroll
  for (int mk = 1; mk < 64; mk <<= 1) part += __shfl_xor(part, mk, 64);
  if ((t & 63) == 0) red[t >> 6] = part;
  __syncthreads();
  if (t == 0) out[n] = red[0] + red[1] + red[2] + red[3] + b2[0];
}

// ------------------------------------------------ launch
extern "C" void kernel_launch(void* const* d_in, const int* in_sizes, int n_in,
                              void* d_out, int out_size, void* d_ws, size_t ws_size,
                              hipStream_t stream){
  const int*   subj = (const int*)  d_in[0];
  const int*   obj  = (const int*)  d_in[1];
  const int*   rel  = (const int*)  d_in[2];
  const float* tim  = (const float*)d_in[3];
  const float* ent  = (const float*)d_in[4];
  const float* rele = (const float*)d_in[5];
  const float* in_w = (const float*)d_in[6];
  const float* in_b = (const float*)d_in[7];
  const float* q_w  = (const float*)d_in[8];
  const float* q_b  = (const float*)d_in[9];
  const float* k_w  = (const float*)d_in[10];
  const float* k_b  = (const float*)d_in[11];
  const float* v_w  = (const float*)d_in[12];
  const float* v_b  = (const float*)d_in[13];
  const float* w1   = (const float*)d_in[14];
  const float* b1   = (const float*)d_in[15];
  const float* w2   = (const float*)d_in[16];
  const float* b2   = (const float*)d_in[17];

  char* ws = (char*)d_ws;                                   // ~208 MiB total
  unsigned short* tem  = (unsigned short*)(ws + 0);         //  4,194,304
  float*          cur  = (float*)(ws + 4194304);            // 67,108,864
  unsigned short* enc  = (unsigned short*)(ws + 71303168);  // 33,554,432
  unsigned short* vtb  = (unsigned short*)(ws + 104857600); // 67,108,864 (512 x 128 KB)
  float*          feat = (float*)(ws + 205520896);          //  1,048,576
  unsigned short* wT   = (unsigned short*)(ws + 206569472); //  1,966,080
  float* out = (float*)d_out;

  k_wprep<<<3840, 256, 0, stream>>>(in_w, q_w, k_w, v_w, wT);
  k_temporal<<<4096, 256, 0, stream>>>(tim, (unsigned int*)tem);
  k_inproj<<<1024, 256, 0, stream>>>(subj, obj, rel, ent, rele, wT, in_b, enc);

  for (int h = 0; h < 2; h++){
    for (int l = 0; l < 2; l++){
      int o = h * 2 + l;
      int lzero = (l == 0) ? 1 : 0;
      const unsigned short* wq = wT + 98304 + (size_t)(o * 3 + 0) * 73728;
      const unsigned short* wk = wT + 98304 + (size_t)(o * 3 + 1) * 73728;
      const unsigned short* wv = wT + 98304 + (size_t)(o * 3 + 2) * 73728;
      k_fused2<<<512, 512, 0, stream>>>(enc, cur, tem, wq, wk, wv,
          q_b + o * 256, k_b + o * 256, v_b + o * 256, vtb, tim, lzero);
    }
    k_savefeat<<<512, 256, 0, stream>>>(cur, feat, h);
  }
  k_mlp<<<512, 256, 0, stream>>>(feat, w1, b1, w2, b2, out);
}

// Round 15
// 972.322 us; speedup vs baseline: 1.5979x; 1.5979x over previous
//
#include <hip/hip_runtime.h>
#include <math.h>

typedef __bf16 bf16x8 __attribute__((ext_vector_type(8)));
typedef float  f32x16 __attribute__((ext_vector_type(16)));
typedef unsigned int u32x4 __attribute__((ext_vector_type(4)));

static __device__ __forceinline__ f32x16 MFMA(bf16x8 a, bf16x8 b, f32x16 c){
  return __builtin_amdgcn_mfma_f32_32x32x16_bf16(a, b, c, 0, 0, 0);
}
static __device__ __forceinline__ unsigned short f2bf(float x){
  unsigned int u = __builtin_bit_cast(unsigned int, x);
  u += 0x7fffu + ((u >> 16) & 1u);   // RNE
  return (unsigned short)(u >> 16);
}
static __device__ __forceinline__ unsigned int pack2(float a, float b){
  return ((unsigned int)f2bf(b) << 16) | (unsigned int)f2bf(a);
}
static __device__ __forceinline__ bf16x8 ldfrag(const unsigned short* p){
  return __builtin_bit_cast(bf16x8, *(const uint4*)p);
}
// C-layout row for 32x32x16: row = (reg&3) + 8*(reg>>2) + 4*(lane>>5)
static __device__ __forceinline__ int rowmap(int reg, int lane){
  return (reg & 3) + 8 * (reg >> 2) + 4 * (lane >> 5);
}

// ------------------------------------------------ weight transpose+cast (once)
// in_w part: [col][384] as before (k_inproj unchanged).
// q/k/v parts: k-block-interleaved [k16][col][hi][8] so a GEMM wave's weight
// load is contiguous/coalesced.
__global__ __launch_bounds__(256) void k_wprep(const float* __restrict__ in_w,
    const float* __restrict__ q_w, const float* __restrict__ k_w,
    const float* __restrict__ v_w, unsigned short* __restrict__ wT){
  int idx = blockIdx.x * 256 + threadIdx.x;   // 983040 total
  float v;
  if (idx < 98304){
    int c = idx / 384, k = idx % 384;
    v = in_w[k * 256 + c];
  } else {
    int e = idx - 98304;
    int m = e / 73728, r = e % 73728;
    int k16 = r / 4096, rem = r % 4096;
    int c = rem / 16, kk = rem & 15;
    int k = k16 * 16 + kk;
    int p = m % 3, layer = m / 3;
    const float* src = (p == 0) ? q_w : (p == 1) ? k_w : v_w;
    v = src[(size_t)layer * 73728 + k * 256 + c];
  }
  wT[idx] = f2bf(v);
}

// ------------------------------------------------ temporal emb (bf16, masked)
__global__ __launch_bounds__(256) void k_temporal(const float* __restrict__ tim,
                                                  unsigned int* __restrict__ tem){
  int idx = blockIdx.x * 256 + threadIdx.x;   // 65536*16
  int i = idx & 15, m = idx >> 4;
  float t = tim[m];
  float np = (t > 0.0f) ? 1.0f : 0.0f;
  float dv = expf((float)(2 * i) * (-0.28782313662425576f));
  float arg = t * dv;
  tem[m * 16 + i] = pack2(sinf(arg) * np, cosf(arg) * np);
}

// ------------------------------------------------ input projection (MFMA)
__global__ __launch_bounds__(256, 2) void k_inproj(const int* __restrict__ subj,
    const int* __restrict__ obj, const int* __restrict__ rel,
    const float* __restrict__ ent, const float* __restrict__ rele,
    const unsigned short* __restrict__ inwT, const float* __restrict__ in_b,
    unsigned short* __restrict__ enc){
  __shared__ __align__(16) unsigned short A[64 * 392];  // reused as SB[64*264] after
  int t = threadIdx.x;
  int m0 = blockIdx.x * 64;
  { // gather 64 rows of concat(ent[s],ent[o],rel[r]) as bf16
    int r = t >> 2, c = t & 3;
    int m = m0 + r;
    const float4* s0 = (const float4*)(ent  + (size_t)subj[m] * 128 + c * 32);
    const float4* s1 = (const float4*)(ent  + (size_t)obj[m]  * 128 + c * 32);
    const float4* s2 = (const float4*)(rele + (size_t)rel[m]  * 128 + c * 32);
    unsigned int* dst = (unsigned int*)&A[r * 392];
#pragma unroll
    for (int j = 0; j < 8; j++){
      float4 f0 = s0[j], f1 = s1[j], f2 = s2[j];
      dst[c * 16 + 2 * j]           = pack2(f0.x, f0.y);
      dst[c * 16 + 2 * j + 1]       = pack2(f0.z, f0.w);
      dst[64 + c * 16 + 2 * j]      = pack2(f1.x, f1.y);
      dst[64 + c * 16 + 2 * j + 1]  = pack2(f1.z, f1.w);
      dst[128 + c * 16 + 2 * j]     = pack2(f2.x, f2.y);
      dst[128 + c * 16 + 2 * j + 1] = pack2(f2.z, f2.w);
    }
  }
  __syncthreads();
  int w = t >> 6, lane = t & 63;
  int lrow = lane & 31, khalf = (lane >> 5) * 8;
  int colA = (w * 2) * 32 + lrow, colB = colA + 32;
  f32x16 acc[2][2] = {};
  bf16x8 pb0 = ldfrag(&inwT[(size_t)colA * 384 + khalf]);
  bf16x8 pb1 = ldfrag(&inwT[(size_t)colB * 384 + khalf]);
  for (int ks = 0; ks < 24; ks++){
    int koff = ks * 16 + khalf;
    bf16x8 a0 = ldfrag(&A[lrow * 392 + koff]);
    bf16x8 a1 = ldfrag(&A[(32 + lrow) * 392 + koff]);
    bf16x8 b0 = pb0, b1 = pb1;
    if (ks < 23){
      pb0 = ldfrag(&inwT[(size_t)colA * 384 + koff + 16]);
      pb1 = ldfrag(&inwT[(size_t)colB * 384 + koff + 16]);
    }
    acc[0][0] = MFMA(a0, b0, acc[0][0]);
    acc[1][0] = MFMA(a1, b0, acc[1][0]);
    acc[0][1] = MFMA(a0, b1, acc[0][1]);
    acc[1][1] = MFMA(a1, b1, acc[1][1]);
  }
  float bs0 = in_b[colA], bs1 = in_b[colB];
  __syncthreads();            // A dead; reuse as SB[64][264]
#pragma unroll
  for (int rt = 0; rt < 2; rt++)
#pragma unroll
    for (int reg = 0; reg < 16; reg++){
      int row = rt * 32 + rowmap(reg, lane);
      A[row * 264 + colA] = f2bf(acc[rt][0][reg] + bs0);
      A[row * 264 + colB] = f2bf(acc[rt][1][reg] + bs1);
    }
  __syncthreads();
  {
    int r = t >> 2, s = t & 3;
    const uint4* src = (const uint4*)&A[r * 264 + s * 64];
    uint4* dst = (uint4*)(enc + ((size_t)m0 + r) * 256 + s * 64);
#pragma unroll
    for (int j = 0; j < 8; j++) dst[j] = src[j];
  }
}

// ------------------------------------------------ Q,K,V projections (MFMA)
// 52.5 KB LDS -> 3 blocks/CU. THREE separate GEMM passes (Q, K, V): 64-AGPR
// accumulator + depth-2 named-scalar prefetch, coalesced k-block weights
// (R12-verified). K -> kb plain rows; Q -> qb in k-block-interleaved layout
// [k16][query][hi][8] so k_attn's qf loads coalesce; V^T staged in 2 halves.

#define LOADA(KS, A0, A1)                                                        \
  do {                                                                           \
    if ((KS) < 16){                                                              \
      (A0) = ldfrag((const unsigned short*)(a0p + (((KS) * 32 + hi * 16) ^ aswz))); \
      (A1) = ldfrag((const unsigned short*)(a1p + (((KS) * 32 + hi * 16) ^ aswz))); \
    } else {                                                                     \
      int toff_ = ((KS) - 16) * 32 + hi * 16;                                    \
      (A0) = ldfrag((const unsigned short*)(a0p + 512 + (toff_ ^ (aswz & 48)))); \
      (A1) = ldfrag((const unsigned short*)(a1p + 512 + (toff_ ^ (aswz & 48)))); \
    }                                                                            \
  } while (0)

#define GEMM_PASS(WP, ACC)                                                       \
  do {                                                                           \
    bf16x8 w0A = ldfrag(&(WP)[colA * 16 + khalf]);                               \
    bf16x8 w0B = ldfrag(&(WP)[colB * 16 + khalf]);                               \
    bf16x8 w1A = ldfrag(&(WP)[4096 + colA * 16 + khalf]);                        \
    bf16x8 w1B = ldfrag(&(WP)[4096 + colB * 16 + khalf]);                        \
    _Pragma("unroll")                                                            \
    for (int k2 = 0; k2 < 9; k2++){                                              \
      int ks = 2 * k2;                                                           \
      {                                                                          \
        bf16x8 a0, a1; LOADA(ks, a0, a1);                                        \
        bf16x8 u0 = w0A, u1 = w0B;                                               \
        if (k2 < 8){                                                             \
          int kbase = (ks + 2) * 4096;                                           \
          w0A = ldfrag(&(WP)[kbase + colA * 16 + khalf]);                        \
          w0B = ldfrag(&(WP)[kbase + colB * 16 + khalf]);                        \
        }                                                                        \
        ACC[0][0] = MFMA(a0, u0, ACC[0][0]);                                     \
        ACC[1][0] = MFMA(a1, u0, ACC[1][0]);                                     \
        ACC[0][1] = MFMA(a0, u1, ACC[0][1]);                                     \
        ACC[1][1] = MFMA(a1, u1, ACC[1][1]);                                     \
      }                                                                          \
      {                                                                          \
        bf16x8 a0, a1; LOADA(ks + 1, a0, a1);                                    \
        bf16x8 u0 = w1A, u1 = w1B;                                               \
        if (k2 < 8){                                                             \
          int kbase = (ks + 3) * 4096;                                           \
          w1A = ldfrag(&(WP)[kbase + colA * 16 + khalf]);                        \
          w1B = ldfrag(&(WP)[kbase + colB * 16 + khalf]);                        \
        }                                                                        \
        ACC[0][0] = MFMA(a0, u0, ACC[0][0]);                                     \
        ACC[1][0] = MFMA(a1, u0, ACC[1][0]);                                     \
        ACC[0][1] = MFMA(a0, u1, ACC[0][1]);                                     \
        ACC[1][1] = MFMA(a1, u1, ACC[1][1]);                                     \
      }                                                                          \
    }                                                                            \
  } while (0)

// K store: plain [query][ch] rows (R12-verified)
#define STORE_RC(ACC, BIAS, OUT)                                                 \
  do {                                                                           \
    float bs0 = (BIAS)[colA], bs1 = (BIAS)[colB];                                \
    _Pragma("unroll")                                                            \
    for (int rt = 0; rt < 2; rt++){                                              \
      __syncthreads();                                                           \
      _Pragma("unroll")                                                          \
      for (int reg = 0; reg < 16; reg++){                                        \
        int row = rowmap(reg, lane);                                             \
        SB[row * 264 + colA] = f2bf(ACC[rt][0][reg] + bs0);                      \
        SB[row * 264 + colB] = f2bf(ACC[rt][1][reg] + bs1);                      \
      }                                                                          \
      __syncthreads();                                                           \
      int r = t >> 3, s = t & 7;                                                 \
      const uint4* src = (const uint4*)&SB[r * 264];                             \
      uint4* dst = (uint4*)((OUT) + ((size_t)nn * 256 + r0 + rt * 32 + r) * 256);\
      _Pragma("unroll")                                                          \
      for (int j = 0; j < 4; j++) dst[s * 4 + j] = src[s * 4 + j];               \
    }                                                                            \
  } while (0)

// Q store: k-block-interleaved [k16][query][hi][8] per nn:
// elem(query,ch) at nn*65536 + (ch>>4)*4096 + query*16 + (ch&15)
#define STORE_Q(ACC, BIAS, OUT)                                                  \
  do {                                                                           \
    float bs0 = (BIAS)[colA], bs1 = (BIAS)[colB];                                \
    _Pragma("unroll")                                                            \
    for (int rt = 0; rt < 2; rt++){                                              \
      __syncthreads();                                                           \
      _Pragma("unroll")                                                          \
      for (int reg = 0; reg < 16; reg++){                                        \
        int row = rowmap(reg, lane);                                             \
        SB[row * 264 + colA] = f2bf(ACC[rt][0][reg] + bs0);                      \
        SB[row * 264 + colB] = f2bf(ACC[rt][1][reg] + bs1);                      \
      }                                                                          \
      __syncthreads();                                                           \
      int qr = t & 31, mb = t >> 5;                                              \
      _Pragma("unroll")                                                          \
      for (int it = 0; it < 4; it++){                                            \
        int m = it * 8 + mb;                                                     \
        uint4 val = *(const uint4*)&SB[qr * 264 + m * 8];                        \
        *(uint4*)((OUT) + (size_t)nn * 65536 + (m >> 1) * 4096 +                 \
                  (r0 + rt * 32 + qr) * 16 + (m & 1) * 8) = val;                 \
      }                                                                          \
    }                                                                            \
  } while (0)

__global__ __launch_bounds__(256, 3) void k_qkv(const unsigned short* __restrict__ enc,
    const float* __restrict__ cur, const unsigned short* __restrict__ tem,
    const unsigned short* __restrict__ wq, const unsigned short* __restrict__ wk,
    const unsigned short* __restrict__ wv, const float* __restrict__ bq,
    const float* __restrict__ bk, const float* __restrict__ bv,
    int chunk, int lzero,
    unsigned short* __restrict__ qb, unsigned short* __restrict__ kb,
    unsigned short* __restrict__ vtb){
  __shared__ __align__(16) unsigned short A[64 * 288];   // 36,864 B, swizzled 576-B rows
  __shared__ __align__(16) unsigned short SB[32 * 264];  // 16,896 B (= VT[128][66])
  char* Ab = (char*)A;
  int t = threadIdx.x;
  int nn = blockIdx.x >> 2;
  int n  = chunk * 256 + nn;
  int r0 = (blockIdx.x & 3) * 64;
  int w = t >> 6, lane = t & 63;
  int lrow = lane & 31, hi = lane >> 5, khalf = hi * 8;
  int colA = w * 64 + lrow, colB = colA + 32;

  { // gather 64 ci rows (enc | cur | zeros) + tem -> swizzled A
    int r = t >> 2, c4 = t & 3;
    int grow = r0 + r;
    int swz = (r & 7) << 4;
    char* dst = Ab + r * 576;
    if (grow < 128){
      const uint4* s4 = (const uint4*)(enc + ((size_t)n * 128 + grow) * 256 + c4 * 64);
#pragma unroll
      for (int j = 0; j < 8; j++)
        *(uint4*)(dst + ((c4 * 128 + j * 16) ^ swz)) = s4[j];
    } else if (!lzero){
      const float4* s4 = (const float4*)(cur + ((size_t)n * 128 + grow - 128) * 256 + c4 * 64);
#pragma unroll
      for (int j = 0; j < 8; j++){
        float4 fa = s4[2 * j], fb = s4[2 * j + 1];
        uint4 u = make_uint4(pack2(fa.x, fa.y), pack2(fa.z, fa.w),
                             pack2(fb.x, fb.y), pack2(fb.z, fb.w));
        *(uint4*)(dst + ((c4 * 128 + j * 16) ^ swz)) = u;
      }
    } else {
      uint4 z = make_uint4(0, 0, 0, 0);
#pragma unroll
      for (int j = 0; j < 8; j++)
        *(uint4*)(dst + ((c4 * 128 + j * 16) ^ swz)) = z;
    }
    int jr = (grow < 128) ? grow : grow - 128;
    *(uint4*)(dst + 512 + ((c4 * 16) ^ (swz & 48))) =
        *(const uint4*)(tem + ((size_t)n * 128 + jr) * 32 + c4 * 8);
  }
  __syncthreads();

  int aswz = (lrow & 7) << 4;            // (32+lrow)&7 == lrow&7
  const char* a0p = Ab + lrow * 576;
  const char* a1p = Ab + (32 + lrow) * 576;

  // ---- pass 1: Q (interleaved out) ----
  {
    f32x16 acc[2][2] = {};
    GEMM_PASS(wq, acc);
    STORE_Q(acc, bq, qb);
  }
  // ---- pass 2: K ----
  {
    f32x16 acc[2][2] = {};
    GEMM_PASS(wk, acc);
    STORE_RC(acc, bk, kb);
  }
  // ---- pass 3: V (transposed out via SB halves) ----
  {
    f32x16 acc[2][2] = {};
    GEMM_PASS(wv, acc);
    float bs0 = bv[colA], bs1 = bv[colB];
#pragma unroll
    for (int half = 0; half < 2; half++){
      __syncthreads();
      if ((w >> 1) == half){          // waves owning d in [half*128, half*128+128)
        int dA = colA & 127, dB = colB & 127;
#pragma unroll
        for (int rt = 0; rt < 2; rt++)
#pragma unroll
          for (int reg = 0; reg < 16; reg++){
            int kl = rt * 32 + rowmap(reg, lane);
            SB[dA * 66 + kl] = f2bf(acc[rt][0][reg] + bs0);
            SB[dB * 66 + kl] = f2bf(acc[rt][1][reg] + bs1);
          }
      }
      __syncthreads();
#pragma unroll
      for (int it = 0; it < 4; it++){
        int dl = it * 32 + (t >> 3), j = t & 7;
        const unsigned int* vs = (const unsigned int*)&SB[dl * 66];
        uint4 val = make_uint4(vs[j * 4], vs[j * 4 + 1], vs[j * 4 + 2], vs[j * 4 + 3]);
        *(uint4*)(vtb + ((size_t)nn * 256 + half * 128 + dl) * 256 + r0 + j * 8) = val;
      }
    }
  }
}

// ------------------------------------------------ attention, fused per-sequence
// 8 waves = 512 threads, one block per nn. Swapped QK^T (S^T: lane=q, regs=keys),
// in-register softmax (max-free, deferred normalization), masked-tile skipping,
// K then V^T staged in one XOR-swizzled 128 KB LDS buffer. qb is k-block
// interleaved -> coalesced qf loads. Folds k_savefeat (hsave>=0).
__global__ __launch_bounds__(512, 2) void k_attn(const unsigned short* __restrict__ qb,
    const unsigned short* __restrict__ kb, const unsigned short* __restrict__ vtb,
    unsigned short* __restrict__ enc, float* __restrict__ cur,
    const float* __restrict__ tim, float* __restrict__ feat,
    int chunk, int lzero, int hsave){
  __shared__ __align__(16) unsigned short KV[65536];   // 131072 B: [256 rows][512 B], byte ^= (row&7)<<4
  __shared__ float TS[128];
  char* KVb = (char*)KV;
  int t = threadIdx.x;
  int nn = blockIdx.x;
  int n  = chunk * 256 + nn;
  int w = t >> 6, lane = t & 63;
  int lrow = lane & 31, hi = lane >> 5;
  int hi4 = hi * 4;
  int q = w * 32 + lrow;
  const unsigned short* qn = qb  + (size_t)nn * 65536;
  const unsigned short* kn = kb  + (size_t)nn * 65536;
  const unsigned short* vn = vtb + (size_t)nn * 65536;

  if (t < 128) TS[t] = tim[(size_t)n * 128 + t];

  // ---- preload Q fragments (interleaved layout: coalesced) ----
  bf16x8 qf[16];
#pragma unroll
  for (int ks = 0; ks < 16; ks++)
    qf[ks] = ldfrag(&qn[ks * 4096 + q * 16 + hi * 8]);

  // ---- stage K[key][d] -> LDS, swizzled; wave w owns rows [32w, 32w+32) ----
#pragma unroll
  for (int it = 0; it < 16; it++){
    int row = w * 32 + it * 2 + hi;
    uint4 v = *(const uint4*)(kn + (size_t)row * 256 + lrow * 8);
    *(uint4*)(KVb + row * 512 + ((lrow * 16) ^ ((row & 7) << 4))) = v;
  }
  __syncthreads();

  // ---- issue V^T loads early (written to LDS after QK phase) ----
  uint4 vst[16];
#pragma unroll
  for (int it = 0; it < 16; it++){
    int row = w * 32 + it * 2 + hi;
    vst[it] = *(const uint4*)(vn + (size_t)row * 256 + lrow * 8);
  }

  // key-time==0 masks for keys 0..127 (lane-uniform words)
  unsigned long long mm0 = __ballot(TS[lane] == 0.0f);
  unsigned long long mm1 = __ballot(TS[lane + 64] == 0.0f);
  unsigned int tz32[4] = { (unsigned int)mm0, (unsigned int)(mm0 >> 32),
                           (unsigned int)mm1, (unsigned int)(mm1 >> 32) };

  bool top = (q < 128);
  int qcmp = q & 127;
  float sum = 0.0f;
  unsigned int pw[8][8];   // packed bf16 e-pairs per key-tile

  // ---- QK^T (swapped: C[row=key][col=q]) + mask + exp + pack, per tile ----
#pragma unroll
  for (int kt = 0; kt < 8; kt++){
    bool need = top ? (kt <= w) : ((kt <= w - 4) || (kt == w));   // wave-uniform
    if (need){
      f32x16 s = {};
#pragma unroll
      for (int ks = 0; ks < 16; ks++){
        int row = kt * 32 + lrow;
        bf16x8 a = ldfrag((const unsigned short*)(KVb + row * 512 +
                          ((ks * 32 + hi * 16) ^ ((row & 7) << 4))));
        s = MFMA(a, qf[ks], s);
      }
#pragma unroll
      for (int j = 0; j < 8; j++){
        float e2[2];
#pragma unroll
        for (int u = 0; u < 2; u++){
          int r = 2 * j + u;
          int pat = (r & 3) + 8 * (r >> 2);
          int key = kt * 32 + pat + hi4;
          float sv = s[r] * 0.0625f;
          bool masked;
          if (kt < 4){
            bool tzb = (tz32[kt] >> (pat + hi4)) & 1;
            masked = (key >= qcmp) || tzb;
          } else {
            masked = top || (key != q);
          }
          float e = masked ? 0.0f : __expf(sv);
          sum += e;
          e2[u] = e;
        }
        pw[kt][j] = pack2(e2[0], e2[1]);
      }
    }
  }
  sum += __shfl_xor(sum, 32, 64);
  float rs = (sum > 0.0f) ? 1.0f / sum : 0.0f;
  bool am = (sum == 0.0f);   // all-masked row -> uniform 1/256 over ALL keys

  // ---- swap buffer to V^T[d][key] ----
  __syncthreads();           // all K reads done
#pragma unroll
  for (int it = 0; it < 16; it++){
    int row = w * 32 + it * 2 + hi;
    *(uint4*)(KVb + row * 512 + ((lrow * 16) ^ ((row & 7) << 4))) = vst[it];
  }
  __syncthreads();

  // ---- PV: O^T[d][q] += V^T-frag x P-frag, masked tiles skipped ----
  f32x16 ov[8] = {};
#pragma unroll
  for (int kt = 0; kt < 8; kt++){
    bool need = top ? (kt <= w) : ((kt <= w - 4) || (kt == w));
    if (need){
      unsigned int s0 = __shfl_xor(pw[kt][0], 32, 64);
      unsigned int s1 = __shfl_xor(pw[kt][1], 32, 64);
      unsigned int s2 = __shfl_xor(pw[kt][2], 32, 64);
      unsigned int s3 = __shfl_xor(pw[kt][3], 32, 64);
      unsigned int s4 = __shfl_xor(pw[kt][4], 32, 64);
      unsigned int s5 = __shfl_xor(pw[kt][5], 32, 64);
      unsigned int s6 = __shfl_xor(pw[kt][6], 32, 64);
      unsigned int s7 = __shfl_xor(pw[kt][7], 32, 64);
      u32x4 fe = { hi ? s2 : pw[kt][0], hi ? s3 : pw[kt][1],
                   hi ? pw[kt][2] : s0, hi ? pw[kt][3] : s1 };
      u32x4 fo = { hi ? s6 : pw[kt][4], hi ? s7 : pw[kt][5],
                   hi ? pw[kt][6] : s4, hi ? pw[kt][7] : s5 };
      bf16x8 be = __builtin_bit_cast(bf16x8, fe);
      bf16x8 bo = __builtin_bit_cast(bf16x8, fo);
#pragma unroll
      for (int dt = 0; dt < 8; dt++){
        int row = dt * 32 + lrow;
        int swz = (row & 7) << 4;
        bf16x8 a0 = ldfrag((const unsigned short*)(KVb + row * 512 + ((kt * 64 + hi * 16) ^ swz)));
        bf16x8 a1 = ldfrag((const unsigned short*)(KVb + row * 512 + ((kt * 64 + 32 + hi * 16) ^ swz)));
        ov[dt] = MFMA(a0, be, ov[dt]);
        ov[dt] = MFMA(a1, bo, ov[dt]);
      }
    }
  }
  // normalize (deferred); am lanes get zero then the uniform pass below
#pragma unroll
  for (int dt = 0; dt < 8; dt++)
#pragma unroll
    for (int r = 0; r < 16; r++) ov[dt][r] *= rs;

  if (__ballot(am)){   // rare: wave 0 (q=0) structurally; lane-predicated uniform P
    float c = am ? 0.00390625f : 0.0f;
    unsigned int uwd = pack2(c, c);
    u32x4 fu = { uwd, uwd, uwd, uwd };
    bf16x8 bu = __builtin_bit_cast(bf16x8, fu);
#pragma unroll
    for (int s2i = 0; s2i < 16; s2i++){
#pragma unroll
      for (int dt = 0; dt < 8; dt++){
        int row = dt * 32 + lrow;
        bf16x8 a = ldfrag((const unsigned short*)(KVb + row * 512 +
                          ((s2i * 32 + hi * 16) ^ ((row & 7) << 4))));
        ov[dt] = MFMA(a, bu, ov[dt]);
      }
    }
  }

  // ---- epilogue: enc (q<128, bf16) then cur (q>=128, f32 tanh accumulate) ----
  __syncthreads();           // V^T reads done; KV reused for O staging
  if (w < 4){                // bf16 O[q][d], swizzled, lower 64 KB
#pragma unroll
    for (int dt = 0; dt < 8; dt++)
#pragma unroll
      for (int j = 0; j < 8; j++){
        int r = 2 * j;
        int pat = (r & 3) + 8 * (r >> 2);
        int d = dt * 32 + pat + hi4;
        *(unsigned int*)(KVb + q * 512 + ((d * 2) ^ ((q & 7) << 4))) =
            pack2(ov[dt][r], ov[dt][r + 1]);
      }
  }
  __syncthreads();
  {                          // coalesced store of enc
    int row = t >> 2;
    const char* src = KVb + row * 512;
    unsigned short* dst = enc + ((size_t)n * 128 + row) * 256;
    int swz = (row & 7) << 4;
#pragma unroll
    for (int jj = 0; jj < 8; jj++){
      int c = jj * 4 + (t & 3);
      uint4 v = *(const uint4*)(src + ((c * 16) ^ swz));
      *(uint4*)(dst + c * 8) = v;
    }
  }
  __syncthreads();
  if (w >= 4){               // f32 tanh values [qq][d], swizzled, full 128 KB
    int qq = q - 128;
    float tq = TS[qq];
#pragma unroll
    for (int dt = 0; dt < 8; dt++)
#pragma unroll
      for (int j = 0; j < 8; j++){
        int r = 2 * j;
        int pat = (r & 3) + 8 * (r >> 2);
        int d = dt * 32 + pat + hi4;
        float th0 = 0.0f, th1 = 0.0f;
        if (tq > 0.0f){
          th0 = 1.0f - 2.0f / (__expf(2.0f * ov[dt][r]) + 1.0f);
          th1 = 1.0f - 2.0f / (__expf(2.0f * ov[dt][r + 1]) + 1.0f);
        }
        float2 p2 = make_float2(th0, th1);
        *(float2*)(KVb + qq * 1024 + ((d * 4) ^ ((qq & 7) << 4))) = p2;
      }
  }
  __syncthreads();
  {                          // coalesced cur update (RMW unless lzero) + feat fold
    int row = t >> 2;
    int swz = (row & 7) << 4;
    const char* src = KVb + row * 1024;
    float* dst = cur + ((size_t)n * 128 + row) * 256;
#pragma unroll
    for (int jj = 0; jj < 16; jj++){
      int c = jj * 4 + (t & 3);
      float4 v = *(const float4*)(src + ((c * 16) ^ swz));
      if (!lzero){
        float4 o = *(const float4*)(dst + c * 4);
        v.x += o.x; v.y += o.y; v.z += o.z; v.w += o.w;
      }
      *(float4*)(dst + c * 4) = v;
      if (hsave >= 0 && row == 127)
        *(float4*)(feat + (size_t)n * 512 + hsave * 256 + c * 4) = v;
    }
  }
}

// ------------------------------------------------ output MLP head
__global__ __launch_bounds__(256) void k_mlp(const float* __restrict__ feat,
    const float* __restrict__ w1, const float* __restrict__ b1,
    const float* __restrict__ w2, const float* __restrict__ b2,
    float* __restrict__ out){
  __shared__ float F[512];
  __shared__ float red[4];
  int n = blockIdx.x, t = threadIdx.x;
  F[t]       = feat[(size_t)n * 512 + t];
  F[t + 256] = feat[(size_t)n * 512 + 256 + t];
  __syncthreads();
  float acc = 0.0f;
  for (int k4 = 0; k4 < 128; k4++){
    float b0v = w1[(k4 * 4 + 0) * 256 + t];
    float b1v = w1[(k4 * 4 + 1) * 256 + t];
    float b2v = w1[(k4 * 4 + 2) * 256 + t];
    float b3v = w1[(k4 * 4 + 3) * 256 + t];
    const float4 f = *(const float4*)&F[k4 * 4];
    acc = fmaf(f.x, b0v, fmaf(f.y, b1v, fmaf(f.z, b2v, fmaf(f.w, b3v, acc))));
  }
  acc += b1[t];
  float g = 0.5f * acc * (1.0f + erff(acc * 0.7071067811865475f));
  float part = g * w2[t];
#pragma unroll
  for (int mk = 1; mk < 64; mk <<= 1) part += __shfl_xor(part, mk, 64);
  if ((t & 63) == 0) red[t >> 6] = part;
  __syncthreads();
  if (t == 0) out[n] = red[0] + red[1] + red[2] + red[3] + b2[0];
}

// ------------------------------------------------ launch
extern "C" void kernel_launch(void* const* d_in, const int* in_sizes, int n_in,
                              void* d_out, int out_size, void* d_ws, size_t ws_size,
                              hipStream_t stream){
  const int*   subj = (const int*)  d_in[0];
  const int*   obj  = (const int*)  d_in[1];
  const int*   rel  = (const int*)  d_in[2];
  const float* tim  = (const float*)d_in[3];
  const float* ent  = (const float*)d_in[4];
  const float* rele = (const float*)d_in[5];
  const float* in_w = (const float*)d_in[6];
  const float* in_b = (const float*)d_in[7];
  const float* q_w  = (const float*)d_in[8];
  const float* q_b  = (const float*)d_in[9];
  const float* k_w  = (const float*)d_in[10];
  const float* k_b  = (const float*)d_in[11];
  const float* v_w  = (const float*)d_in[12];
  const float* v_b  = (const float*)d_in[13];
  const float* w1   = (const float*)d_in[14];
  const float* b1   = (const float*)d_in[15];
  const float* w2   = (const float*)d_in[16];
  const float* b2   = (const float*)d_in[17];

  char* ws = (char*)d_ws;                                   // ~208 MiB total
  unsigned short* tem  = (unsigned short*)(ws + 0);         //  4,194,304
  float*          cur  = (float*)(ws + 4194304);            // 67,108,864
  unsigned short* enc  = (unsigned short*)(ws + 71303168);  // 33,554,432
  unsigned short* qb   = (unsigned short*)(ws + 104857600); // 33,554,432
  unsigned short* kb   = (unsigned short*)(ws + 138412032); // 33,554,432
  unsigned short* vtb  = (unsigned short*)(ws + 171966464); // 33,554,432
  float*          feat = (float*)(ws + 205520896);          //  1,048,576
  unsigned short* wT   = (unsigned short*)(ws + 206569472); //  1,966,080
  float* out = (float*)d_out;

  k_wprep<<<3840, 256, 0, stream>>>(in_w, q_w, k_w, v_w, wT);
  k_temporal<<<4096, 256, 0, stream>>>(tim, (unsigned int*)tem);
  k_inproj<<<1024, 256, 0, stream>>>(subj, obj, rel, ent, rele, wT, in_b, enc);

  for (int h = 0; h < 2; h++){
    for (int l = 0; l < 2; l++){
      int o = h * 2 + l;
      int lzero = (l == 0) ? 1 : 0;
      int hsave = (l == 1) ? h : -1;
      const unsigned short* wq = wT + 98304 + (size_t)(o * 3 + 0) * 73728;
      const unsigned short* wk = wT + 98304 + (size_t)(o * 3 + 1) * 73728;
      const unsigned short* wv = wT + 98304 + (size_t)(o * 3 + 2) * 73728;
      for (int c = 0; c < 2; c++){
        k_qkv<<<1024, 256, 0, stream>>>(enc, cur, tem, wq, wk, wv,
            q_b + o * 256, k_b + o * 256, v_b + o * 256, c, lzero, qb, kb, vtb);
        k_attn<<<256, 512, 0, stream>>>(qb, kb, vtb, enc, cur, tim, feat,
                                        c, lzero, hsave);
      }
    }
  }
  k_mlp<<<512, 256, 0, stream>>>(feat, w1, b1, w2, b2, out);
}

// Round 16
// 916.463 us; speedup vs baseline: 1.6953x; 1.0610x over previous
//
#include <hip/hip_runtime.h>
#include <math.h>

typedef __bf16 bf16x8 __attribute__((ext_vector_type(8)));
typedef float  f32x16 __attribute__((ext_vector_type(16)));
typedef unsigned int u32x4 __attribute__((ext_vector_type(4)));

static __device__ __forceinline__ f32x16 MFMA(bf16x8 a, bf16x8 b, f32x16 c){
  return __builtin_amdgcn_mfma_f32_32x32x16_bf16(a, b, c, 0, 0, 0);
}
static __device__ __forceinline__ unsigned short f2bf(float x){
  unsigned int u = __builtin_bit_cast(unsigned int, x);
  u += 0x7fffu + ((u >> 16) & 1u);   // RNE
  return (unsigned short)(u >> 16);
}
static __device__ __forceinline__ unsigned int pack2(float a, float b){
  return ((unsigned int)f2bf(b) << 16) | (unsigned int)f2bf(a);
}
static __device__ __forceinline__ bf16x8 ldfrag(const unsigned short* p){
  return __builtin_bit_cast(bf16x8, *(const uint4*)p);
}
// C-layout row for 32x32x16: row = (reg&3) + 8*(reg>>2) + 4*(lane>>5)
static __device__ __forceinline__ int rowmap(int reg, int lane){
  return (reg & 3) + 8 * (reg >> 2) + 4 * (lane >> 5);
}

// ------------------------------------------------ weight transpose+cast (once)
// in_w part: [col][384] (k_inproj unchanged). q/k/v parts: k-block-interleaved
// [k16][col][hi][8] so a GEMM wave's weight load is contiguous/coalesced.
__global__ __launch_bounds__(256) void k_wprep(const float* __restrict__ in_w,
    const float* __restrict__ q_w, const float* __restrict__ k_w,
    const float* __restrict__ v_w, unsigned short* __restrict__ wT){
  int idx = blockIdx.x * 256 + threadIdx.x;   // 983040 total
  float v;
  if (idx < 98304){
    int c = idx / 384, k = idx % 384;
    v = in_w[k * 256 + c];
  } else {
    int e = idx - 98304;
    int m = e / 73728, r = e % 73728;
    int k16 = r / 4096, rem = r % 4096;
    int c = rem / 16, kk = rem & 15;
    int k = k16 * 16 + kk;
    int p = m % 3, layer = m / 3;
    const float* src = (p == 0) ? q_w : (p == 1) ? k_w : v_w;
    v = src[(size_t)layer * 73728 + k * 256 + c];
  }
  wT[idx] = f2bf(v);
}

// ------------------------------------------------ temporal emb (bf16, masked)
__global__ __launch_bounds__(256) void k_temporal(const float* __restrict__ tim,
                                                  unsigned int* __restrict__ tem){
  int idx = blockIdx.x * 256 + threadIdx.x;   // 65536*16
  int i = idx & 15, m = idx >> 4;
  float t = tim[m];
  float np = (t > 0.0f) ? 1.0f : 0.0f;
  float dv = expf((float)(2 * i) * (-0.28782313662425576f));
  float arg = t * dv;
  tem[m * 16 + i] = pack2(sinf(arg) * np, cosf(arg) * np);
}

// ------------------------------------------------ input projection (MFMA)
__global__ __launch_bounds__(256, 2) void k_inproj(const int* __restrict__ subj,
    const int* __restrict__ obj, const int* __restrict__ rel,
    const float* __restrict__ ent, const float* __restrict__ rele,
    const unsigned short* __restrict__ inwT, const float* __restrict__ in_b,
    unsigned short* __restrict__ enc){
  __shared__ __align__(16) unsigned short A[64 * 392];  // reused as SB[64*264] after
  int t = threadIdx.x;
  int m0 = blockIdx.x * 64;
  { // gather 64 rows of concat(ent[s],ent[o],rel[r]) as bf16
    int r = t >> 2, c = t & 3;
    int m = m0 + r;
    const float4* s0 = (const float4*)(ent  + (size_t)subj[m] * 128 + c * 32);
    const float4* s1 = (const float4*)(ent  + (size_t)obj[m]  * 128 + c * 32);
    const float4* s2 = (const float4*)(rele + (size_t)rel[m]  * 128 + c * 32);
    unsigned int* dst = (unsigned int*)&A[r * 392];
#pragma unroll
    for (int j = 0; j < 8; j++){
      float4 f0 = s0[j], f1 = s1[j], f2 = s2[j];
      dst[c * 16 + 2 * j]           = pack2(f0.x, f0.y);
      dst[c * 16 + 2 * j + 1]       = pack2(f0.z, f0.w);
      dst[64 + c * 16 + 2 * j]      = pack2(f1.x, f1.y);
      dst[64 + c * 16 + 2 * j + 1]  = pack2(f1.z, f1.w);
      dst[128 + c * 16 + 2 * j]     = pack2(f2.x, f2.y);
      dst[128 + c * 16 + 2 * j + 1] = pack2(f2.z, f2.w);
    }
  }
  __syncthreads();
  int w = t >> 6, lane = t & 63;
  int lrow = lane & 31, khalf = (lane >> 5) * 8;
  int colA = (w * 2) * 32 + lrow, colB = colA + 32;
  f32x16 acc[2][2] = {};
  bf16x8 pb0 = ldfrag(&inwT[(size_t)colA * 384 + khalf]);
  bf16x8 pb1 = ldfrag(&inwT[(size_t)colB * 384 + khalf]);
  for (int ks = 0; ks < 24; ks++){
    int koff = ks * 16 + khalf;
    bf16x8 a0 = ldfrag(&A[lrow * 392 + koff]);
    bf16x8 a1 = ldfrag(&A[(32 + lrow) * 392 + koff]);
    bf16x8 b0 = pb0, b1 = pb1;
    if (ks < 23){
      pb0 = ldfrag(&inwT[(size_t)colA * 384 + koff + 16]);
      pb1 = ldfrag(&inwT[(size_t)colB * 384 + koff + 16]);
    }
    acc[0][0] = MFMA(a0, b0, acc[0][0]);
    acc[1][0] = MFMA(a1, b0, acc[1][0]);
    acc[0][1] = MFMA(a0, b1, acc[0][1]);
    acc[1][1] = MFMA(a1, b1, acc[1][1]);
  }
  float bs0 = in_b[colA], bs1 = in_b[colB];
  __syncthreads();            // A dead; reuse as SB[64][264]
#pragma unroll
  for (int rt = 0; rt < 2; rt++)
#pragma unroll
    for (int reg = 0; reg < 16; reg++){
      int row = rt * 32 + rowmap(reg, lane);
      A[row * 264 + colA] = f2bf(acc[rt][0][reg] + bs0);
      A[row * 264 + colB] = f2bf(acc[rt][1][reg] + bs1);
    }
  __syncthreads();
  {
    int r = t >> 2, s = t & 3;
    const uint4* src = (const uint4*)&A[r * 264 + s * 64];
    uint4* dst = (uint4*)(enc + ((size_t)m0 + r) * 256 + s * 64);
#pragma unroll
    for (int j = 0; j < 8; j++) dst[j] = src[j];
  }
}

// ------------------------------------------------ Q,K,V projections (MFMA)
// 52.5 KB LDS -> 3 blocks/CU. THREE separate GEMM passes (Q, K, V): 64-AGPR
// accumulator + depth-4 named-scalar weight prefetch ring (8 frags, 18
// explicit steps -- rule #20 safe). Coalesced k-block weights. Q -> qb
// interleaved [k16][query][hi][8]; K plain rows; V^T staged in 2 halves.

#define LOADA(KS, A0, A1)                                                        \
  do {                                                                           \
    if ((KS) < 16){                                                              \
      (A0) = ldfrag((const unsigned short*)(a0p + (((KS) * 32 + hi * 16) ^ aswz))); \
      (A1) = ldfrag((const unsigned short*)(a1p + (((KS) * 32 + hi * 16) ^ aswz))); \
    } else {                                                                     \
      int toff_ = ((KS) - 16) * 32 + hi * 16;                                    \
      (A0) = ldfrag((const unsigned short*)(a0p + 512 + (toff_ ^ (aswz & 48)))); \
      (A1) = ldfrag((const unsigned short*)(a1p + 512 + (toff_ ^ (aswz & 48)))); \
    }                                                                            \
  } while (0)

#define GSTEP(KS, WA, WB, ACC)                                                   \
  do {                                                                           \
    bf16x8 a0, a1; LOADA((KS), a0, a1);                                          \
    bf16x8 u0 = WA, u1 = WB;                                                     \
    if ((KS) + 4 < 18){                                                          \
      int kbase = ((KS) + 4) * 4096;                                             \
      WA = ldfrag(&wp_[kbase + colA * 16 + khalf]);                              \
      WB = ldfrag(&wp_[kbase + colB * 16 + khalf]);                              \
    }                                                                            \
    ACC[0][0] = MFMA(a0, u0, ACC[0][0]);                                         \
    ACC[1][0] = MFMA(a1, u0, ACC[1][0]);                                         \
    ACC[0][1] = MFMA(a0, u1, ACC[0][1]);                                         \
    ACC[1][1] = MFMA(a1, u1, ACC[1][1]);                                         \
  } while (0)

#define GEMM_PASS(WP, ACC)                                                       \
  do {                                                                           \
    const unsigned short* wp_ = (WP);                                            \
    bf16x8 w0A = ldfrag(&wp_[0 * 4096 + colA * 16 + khalf]);                     \
    bf16x8 w0B = ldfrag(&wp_[0 * 4096 + colB * 16 + khalf]);                     \
    bf16x8 w1A = ldfrag(&wp_[1 * 4096 + colA * 16 + khalf]);                     \
    bf16x8 w1B = ldfrag(&wp_[1 * 4096 + colB * 16 + khalf]);                     \
    bf16x8 w2A = ldfrag(&wp_[2 * 4096 + colA * 16 + khalf]);                     \
    bf16x8 w2B = ldfrag(&wp_[2 * 4096 + colB * 16 + khalf]);                     \
    bf16x8 w3A = ldfrag(&wp_[3 * 4096 + colA * 16 + khalf]);                     \
    bf16x8 w3B = ldfrag(&wp_[3 * 4096 + colB * 16 + khalf]);                     \
    GSTEP(0,  w0A, w0B, ACC); GSTEP(1,  w1A, w1B, ACC);                          \
    GSTEP(2,  w2A, w2B, ACC); GSTEP(3,  w3A, w3B, ACC);                          \
    GSTEP(4,  w0A, w0B, ACC); GSTEP(5,  w1A, w1B, ACC);                          \
    GSTEP(6,  w2A, w2B, ACC); GSTEP(7,  w3A, w3B, ACC);                          \
    GSTEP(8,  w0A, w0B, ACC); GSTEP(9,  w1A, w1B, ACC);                          \
    GSTEP(10, w2A, w2B, ACC); GSTEP(11, w3A, w3B, ACC);                          \
    GSTEP(12, w0A, w0B, ACC); GSTEP(13, w1A, w1B, ACC);                          \
    GSTEP(14, w2A, w2B, ACC); GSTEP(15, w3A, w3B, ACC);                          \
    GSTEP(16, w0A, w0B, ACC); GSTEP(17, w1A, w1B, ACC);                          \
  } while (0)

// K store: plain [query][ch] rows (R12-verified)
#define STORE_RC(ACC, BIAS, OUT)                                                 \
  do {                                                                           \
    float bs0 = (BIAS)[colA], bs1 = (BIAS)[colB];                                \
    _Pragma("unroll")                                                            \
    for (int rt = 0; rt < 2; rt++){                                              \
      __syncthreads();                                                           \
      _Pragma("unroll")                                                          \
      for (int reg = 0; reg < 16; reg++){                                        \
        int row = rowmap(reg, lane);                                             \
        SB[row * 264 + colA] = f2bf(ACC[rt][0][reg] + bs0);                      \
        SB[row * 264 + colB] = f2bf(ACC[rt][1][reg] + bs1);                      \
      }                                                                          \
      __syncthreads();                                                           \
      int r = t >> 3, s = t & 7;                                                 \
      const uint4* src = (const uint4*)&SB[r * 264];                             \
      uint4* dst = (uint4*)((OUT) + ((size_t)nn * 256 + r0 + rt * 32 + r) * 256);\
      _Pragma("unroll")                                                          \
      for (int j = 0; j < 4; j++) dst[s * 4 + j] = src[s * 4 + j];               \
    }                                                                            \
  } while (0)

// Q store: k-block-interleaved [k16][query][hi][8] per nn (R15-verified)
#define STORE_Q(ACC, BIAS, OUT)                                                  \
  do {                                                                           \
    float bs0 = (BIAS)[colA], bs1 = (BIAS)[colB];                                \
    _Pragma("unroll")                                                            \
    for (int rt = 0; rt < 2; rt++){                                              \
      __syncthreads();                                                           \
      _Pragma("unroll")                                                          \
      for (int reg = 0; reg < 16; reg++){                                        \
        int row = rowmap(reg, lane);                                             \
        SB[row * 264 + colA] = f2bf(ACC[rt][0][reg] + bs0);                      \
        SB[row * 264 + colB] = f2bf(ACC[rt][1][reg] + bs1);                      \
      }                                                                          \
      __syncthreads();                                                           \
      int qr = t & 31, mb = t >> 5;                                              \
      _Pragma("unroll")                                                          \
      for (int it = 0; it < 4; it++){                                            \
        int m = it * 8 + mb;                                                     \
        uint4 val = *(const uint4*)&SB[qr * 264 + m * 8];                        \
        *(uint4*)((OUT) + (size_t)nn * 65536 + (m >> 1) * 4096 +                 \
                  (r0 + rt * 32 + qr) * 16 + (m & 1) * 8) = val;                 \
      }                                                                          \
    }                                                                            \
  } while (0)

__global__ __launch_bounds__(256, 3) void k_qkv(const unsigned short* __restrict__ enc,
    const float* __restrict__ cur, const unsigned short* __restrict__ tem,
    const unsigned short* __restrict__ wq, const unsigned short* __restrict__ wk,
    const unsigned short* __restrict__ wv, const float* __restrict__ bq,
    const float* __restrict__ bk, const float* __restrict__ bv,
    int chunk, int lzero,
    unsigned short* __restrict__ qb, unsigned short* __restrict__ kb,
    unsigned short* __restrict__ vtb){
  __shared__ __align__(16) unsigned short A[64 * 288];   // 36,864 B, swizzled 576-B rows
  __shared__ __align__(16) unsigned short SB[32 * 264];  // 16,896 B (= VT[128][66])
  char* Ab = (char*)A;
  int t = threadIdx.x;
  int nn = blockIdx.x >> 2;
  int n  = chunk * 256 + nn;
  int r0 = (blockIdx.x & 3) * 64;
  int w = t >> 6, lane = t & 63;
  int lrow = lane & 31, hi = lane >> 5, khalf = hi * 8;
  int colA = w * 64 + lrow, colB = colA + 32;

  { // gather 64 ci rows (enc | cur | zeros) + tem -> swizzled A
    int r = t >> 2, c4 = t & 3;
    int grow = r0 + r;
    int swz = (r & 7) << 4;
    char* dst = Ab + r * 576;
    if (grow < 128){
      const uint4* s4 = (const uint4*)(enc + ((size_t)n * 128 + grow) * 256 + c4 * 64);
#pragma unroll
      for (int j = 0; j < 8; j++)
        *(uint4*)(dst + ((c4 * 128 + j * 16) ^ swz)) = s4[j];
    } else if (!lzero){
      const float4* s4 = (const float4*)(cur + ((size_t)n * 128 + grow - 128) * 256 + c4 * 64);
#pragma unroll
      for (int j = 0; j < 8; j++){
        float4 fa = s4[2 * j], fb = s4[2 * j + 1];
        uint4 u = make_uint4(pack2(fa.x, fa.y), pack2(fa.z, fa.w),
                             pack2(fb.x, fb.y), pack2(fb.z, fb.w));
        *(uint4*)(dst + ((c4 * 128 + j * 16) ^ swz)) = u;
      }
    } else {
      uint4 z = make_uint4(0, 0, 0, 0);
#pragma unroll
      for (int j = 0; j < 8; j++)
        *(uint4*)(dst + ((c4 * 128 + j * 16) ^ swz)) = z;
    }
    int jr = (grow < 128) ? grow : grow - 128;
    *(uint4*)(dst + 512 + ((c4 * 16) ^ (swz & 48))) =
        *(const uint4*)(tem + ((size_t)n * 128 + jr) * 32 + c4 * 8);
  }
  __syncthreads();

  int aswz = (lrow & 7) << 4;            // (32+lrow)&7 == lrow&7
  const char* a0p = Ab + lrow * 576;
  const char* a1p = Ab + (32 + lrow) * 576;

  // ---- pass 1: Q (interleaved out) ----
  {
    f32x16 acc[2][2] = {};
    GEMM_PASS(wq, acc);
    STORE_Q(acc, bq, qb);
  }
  // ---- pass 2: K ----
  {
    f32x16 acc[2][2] = {};
    GEMM_PASS(wk, acc);
    STORE_RC(acc, bk, kb);
  }
  // ---- pass 3: V (transposed out via SB halves) ----
  {
    f32x16 acc[2][2] = {};
    GEMM_PASS(wv, acc);
    float bs0 = bv[colA], bs1 = bv[colB];
#pragma unroll
    for (int half = 0; half < 2; half++){
      __syncthreads();
      if ((w >> 1) == half){          // waves owning d in [half*128, half*128+128)
        int dA = colA & 127, dB = colB & 127;
#pragma unroll
        for (int rt = 0; rt < 2; rt++)
#pragma unroll
          for (int reg = 0; reg < 16; reg++){
            int kl = rt * 32 + rowmap(reg, lane);
            SB[dA * 66 + kl] = f2bf(acc[rt][0][reg] + bs0);
            SB[dB * 66 + kl] = f2bf(acc[rt][1][reg] + bs1);
          }
      }
      __syncthreads();
#pragma unroll
      for (int it = 0; it < 4; it++){
        int dl = it * 32 + (t >> 3), j = t & 7;
        const unsigned int* vs = (const unsigned int*)&SB[dl * 66];
        uint4 val = make_uint4(vs[j * 4], vs[j * 4 + 1], vs[j * 4 + 2], vs[j * 4 + 3]);
        *(uint4*)(vtb + ((size_t)nn * 256 + half * 128 + dl) * 256 + r0 + j * 8) = val;
      }
    }
  }
}

// ------------------------------------------------ attention, fused per-sequence
// 8 waves = 512 threads, one block per nn. Swapped QK^T, in-register max-free
// softmax, masked-tile skipping. K then V^T staged in one XOR-swizzled 128 KB
// LDS buffer. V loaded AFTER QK (no 64-reg vst park); P kept in compact
// pw[5][8] (slot = kt<4 ? kt : 4 -- a wave needs <=5 tiles). Coalesced qf
// (interleaved qb). Folds k_savefeat (hsave>=0).
__global__ __launch_bounds__(512, 2) void k_attn(const unsigned short* __restrict__ qb,
    const unsigned short* __restrict__ kb, const unsigned short* __restrict__ vtb,
    unsigned short* __restrict__ enc, float* __restrict__ cur,
    const float* __restrict__ tim, float* __restrict__ feat,
    int chunk, int lzero, int hsave){
  __shared__ __align__(16) unsigned short KV[65536];   // 131072 B: [256 rows][512 B], byte ^= (row&7)<<4
  __shared__ float TS[128];
  char* KVb = (char*)KV;
  int t = threadIdx.x;
  int nn = blockIdx.x;
  int n  = chunk * 256 + nn;
  int w = t >> 6, lane = t & 63;
  int lrow = lane & 31, hi = lane >> 5;
  int hi4 = hi * 4;
  int q = w * 32 + lrow;
  const unsigned short* qn = qb  + (size_t)nn * 65536;
  const unsigned short* kn = kb  + (size_t)nn * 65536;
  const unsigned short* vn = vtb + (size_t)nn * 65536;

  if (t < 128) TS[t] = tim[(size_t)n * 128 + t];

  // ---- preload Q fragments (interleaved layout: coalesced) ----
  bf16x8 qf[16];
#pragma unroll
  for (int ks = 0; ks < 16; ks++)
    qf[ks] = ldfrag(&qn[ks * 4096 + q * 16 + hi * 8]);

  // ---- stage K[key][d] -> LDS, swizzled; wave w owns rows [32w, 32w+32) ----
#pragma unroll
  for (int it = 0; it < 16; it++){
    int row = w * 32 + it * 2 + hi;
    uint4 v = *(const uint4*)(kn + (size_t)row * 256 + lrow * 8);
    *(uint4*)(KVb + row * 512 + ((lrow * 16) ^ ((row & 7) << 4))) = v;
  }
  __syncthreads();

  // key-time==0 masks for keys 0..127 (lane-uniform words)
  unsigned long long mm0 = __ballot(TS[lane] == 0.0f);
  unsigned long long mm1 = __ballot(TS[lane + 64] == 0.0f);
  unsigned int tz32[4] = { (unsigned int)mm0, (unsigned int)(mm0 >> 32),
                           (unsigned int)mm1, (unsigned int)(mm1 >> 32) };

  bool top = (q < 128);
  int qcmp = q & 127;
  float sum = 0.0f;
  unsigned int pw[5][8];   // packed bf16 e-pairs; slot = kt<4 ? kt : 4

  // ---- QK^T (swapped: C[row=key][col=q]) + mask + exp + pack, per tile ----
#pragma unroll
  for (int kt = 0; kt < 8; kt++){
    const int slot = (kt < 4) ? kt : 4;
    bool need = top ? (kt <= w) : ((kt <= w - 4) || (kt == w));   // wave-uniform
    if (need){
      f32x16 s = {};
#pragma unroll
      for (int ks = 0; ks < 16; ks++){
        int row = kt * 32 + lrow;
        bf16x8 a = ldfrag((const unsigned short*)(KVb + row * 512 +
                          ((ks * 32 + hi * 16) ^ ((row & 7) << 4))));
        s = MFMA(a, qf[ks], s);
      }
#pragma unroll
      for (int j = 0; j < 8; j++){
        float e2[2];
#pragma unroll
        for (int u = 0; u < 2; u++){
          int r = 2 * j + u;
          int pat = (r & 3) + 8 * (r >> 2);
          int key = kt * 32 + pat + hi4;
          float sv = s[r] * 0.0625f;
          bool masked;
          if (kt < 4){
            bool tzb = (tz32[kt] >> (pat + hi4)) & 1;
            masked = (key >= qcmp) || tzb;
          } else {
            masked = top || (key != q);
          }
          float e = masked ? 0.0f : __expf(sv);
          sum += e;
          e2[u] = e;
        }
        pw[slot][j] = pack2(e2[0], e2[1]);
      }
    }
  }
  sum += __shfl_xor(sum, 32, 64);
  float rs = (sum > 0.0f) ? 1.0f / sum : 0.0f;
  bool am = (sum == 0.0f);   // all-masked row -> uniform 1/256 over ALL keys

  // ---- swap buffer to V^T[d][key]: load AFTER QK (qf dead; no reg park) ----
  __syncthreads();           // all K reads done
#pragma unroll
  for (int it = 0; it < 16; it++){
    int row = w * 32 + it * 2 + hi;
    uint4 v = *(const uint4*)(vn + (size_t)row * 256 + lrow * 8);
    *(uint4*)(KVb + row * 512 + ((lrow * 16) ^ ((row & 7) << 4))) = v;
  }
  __syncthreads();

  // ---- PV: O^T[d][q] += V^T-frag x P-frag, masked tiles skipped ----
  f32x16 ov[8] = {};
#pragma unroll
  for (int kt = 0; kt < 8; kt++){
    const int slot = (kt < 4) ? kt : 4;
    bool need = top ? (kt <= w) : ((kt <= w - 4) || (kt == w));
    if (need){
      unsigned int s0 = __shfl_xor(pw[slot][0], 32, 64);
      unsigned int s1 = __shfl_xor(pw[slot][1], 32, 64);
      unsigned int s2 = __shfl_xor(pw[slot][2], 32, 64);
      unsigned int s3 = __shfl_xor(pw[slot][3], 32, 64);
      unsigned int s4 = __shfl_xor(pw[slot][4], 32, 64);
      unsigned int s5 = __shfl_xor(pw[slot][5], 32, 64);
      unsigned int s6 = __shfl_xor(pw[slot][6], 32, 64);
      unsigned int s7 = __shfl_xor(pw[slot][7], 32, 64);
      u32x4 fe = { hi ? s2 : pw[slot][0], hi ? s3 : pw[slot][1],
                   hi ? pw[slot][2] : s0, hi ? pw[slot][3] : s1 };
      u32x4 fo = { hi ? s6 : pw[slot][4], hi ? s7 : pw[slot][5],
                   hi ? pw[slot][6] : s4, hi ? pw[slot][7] : s5 };
      bf16x8 be = __builtin_bit_cast(bf16x8, fe);
      bf16x8 bo = __builtin_bit_cast(bf16x8, fo);
#pragma unroll
      for (int dt = 0; dt < 8; dt++){
        int row = dt * 32 + lrow;
        int swz = (row & 7) << 4;
        bf16x8 a0 = ldfrag((const unsigned short*)(KVb + row * 512 + ((kt * 64 + hi * 16) ^ swz)));
        bf16x8 a1 = ldfrag((const unsigned short*)(KVb + row * 512 + ((kt * 64 + 32 + hi * 16) ^ swz)));
        ov[dt] = MFMA(a0, be, ov[dt]);
        ov[dt] = MFMA(a1, bo, ov[dt]);
      }
    }
  }
  // normalize (deferred); am lanes get zero then the uniform pass below
#pragma unroll
  for (int dt = 0; dt < 8; dt++)
#pragma unroll
    for (int r = 0; r < 16; r++) ov[dt][r] *= rs;

  if (__ballot(am)){   // rare: wave 0 (q=0) structurally; lane-predicated uniform P
    float c = am ? 0.00390625f : 0.0f;
    unsigned int uwd = pack2(c, c);
    u32x4 fu = { uwd, uwd, uwd, uwd };
    bf16x8 bu = __builtin_bit_cast(bf16x8, fu);
#pragma unroll
    for (int s2i = 0; s2i < 16; s2i++){
#pragma unroll
      for (int dt = 0; dt < 8; dt++){
        int row = dt * 32 + lrow;
        bf16x8 a = ldfrag((const unsigned short*)(KVb + row * 512 +
                          ((s2i * 32 + hi * 16) ^ ((row & 7) << 4))));
        ov[dt] = MFMA(a, bu, ov[dt]);
      }
    }
  }

  // ---- epilogue: enc (q<128, bf16) then cur (q>=128, f32 tanh accumulate) ----
  __syncthreads();           // V^T reads done; KV reused for O staging
  if (w < 4){                // bf16 O[q][d], swizzled, lower 64 KB
#pragma unroll
    for (int dt = 0; dt < 8; dt++)
#pragma unroll
      for (int j = 0; j < 8; j++){
        int r = 2 * j;
        int pat = (r & 3) + 8 * (r >> 2);
        int d = dt * 32 + pat + hi4;
        *(unsigned int*)(KVb + q * 512 + ((d * 2) ^ ((q & 7) << 4))) =
            pack2(ov[dt][r], ov[dt][r + 1]);
      }
  }
  __syncthreads();
  {                          // coalesced store of enc
    int row = t >> 2;
    const char* src = KVb + row * 512;
    unsigned short* dst = enc + ((size_t)n * 128 + row) * 256;
    int swz = (row & 7) << 4;
#pragma unroll
    for (int jj = 0; jj < 8; jj++){
      int c = jj * 4 + (t & 3);
      uint4 v = *(const uint4*)(src + ((c * 16) ^ swz));
      *(uint4*)(dst + c * 8) = v;
    }
  }
  __syncthreads();
  if (w >= 4){               // f32 tanh values [qq][d], swizzled, full 128 KB
    int qq = q - 128;
    float tq = TS[qq];
#pragma unroll
    for (int dt = 0; dt < 8; dt++)
#pragma unroll
      for (int j = 0; j < 8; j++){
        int r = 2 * j;
        int pat = (r & 3) + 8 * (r >> 2);
        int d = dt * 32 + pat + hi4;
        float th0 = 0.0f, th1 = 0.0f;
        if (tq > 0.0f){
          th0 = 1.0f - 2.0f / (__expf(2.0f * ov[dt][r]) + 1.0f);
          th1 = 1.0f - 2.0f / (__expf(2.0f * ov[dt][r + 1]) + 1.0f);
        }
        float2 p2 = make_float2(th0, th1);
        *(float2*)(KVb + qq * 1024 + ((d * 4) ^ ((qq & 7) << 4))) = p2;
      }
  }
  __syncthreads();
  {                          // coalesced cur update (RMW unless lzero) + feat fold
    int row = t >> 2;
    int swz = (row & 7) << 4;
    const char* src = KVb + row * 1024;
    float* dst = cur + ((size_t)n * 128 + row) * 256;
#pragma unroll
    for (int jj = 0; jj < 16; jj++){
      int c = jj * 4 + (t & 3);
      float4 v = *(const float4*)(src + ((c * 16) ^ swz));
      if (!lzero){
        float4 o = *(const float4*)(dst + c * 4);
        v.x += o.x; v.y += o.y; v.z += o.z; v.w += o.w;
      }
      *(float4*)(dst + c * 4) = v;
      if (hsave >= 0 && row == 127)
        *(float4*)(feat + (size_t)n * 512 + hsave * 256 + c * 4) = v;
    }
  }
}

// ------------------------------------------------ output MLP head
__global__ __launch_bounds__(256) void k_mlp(const float* __restrict__ feat,
    const float* __restrict__ w1, const float* __restrict__ b1,
    const float* __restrict__ w2, const float* __restrict__ b2,
    float* __restrict__ out){
  __shared__ float F[512];
  __shared__ float red[4];
  int n = blockIdx.x, t = threadIdx.x;
  F[t]       = feat[(size_t)n * 512 + t];
  F[t + 256] = feat[(size_t)n * 512 + 256 + t];
  __syncthreads();
  float acc = 0.0f;
  for (int k4 = 0; k4 < 128; k4++){
    float b0v = w1[(k4 * 4 + 0) * 256 + t];
    float b1v = w1[(k4 * 4 + 1) * 256 + t];
    float b2v = w1[(k4 * 4 + 2) * 256 + t];
    float b3v = w1[(k4 * 4 + 3) * 256 + t];
    const float4 f = *(const float4*)&F[k4 * 4];
    acc = fmaf(f.x, b0v, fmaf(f.y, b1v, fmaf(f.z, b2v, fmaf(f.w, b3v, acc))));
  }
  acc += b1[t];
  float g = 0.5f * acc * (1.0f + erff(acc * 0.7071067811865475f));
  float part = g * w2[t];
#pragma unroll
  for (int mk = 1; mk < 64; mk <<= 1) part += __shfl_xor(part, mk, 64);
  if ((t & 63) == 0) red[t >> 6] = part;
  __syncthreads();
  if (t == 0) out[n] = red[0] + red[1] + red[2] + red[3] + b2[0];
}

// ------------------------------------------------ launch
extern "C" void kernel_launch(void* const* d_in, const int* in_sizes, int n_in,
                              void* d_out, int out_size, void* d_ws, size_t ws_size,
                              hipStream_t stream){
  const int*   subj = (const int*)  d_in[0];
  const int*   obj  = (const int*)  d_in[1];
  const int*   rel  = (const int*)  d_in[2];
  const float* tim  = (const float*)d_in[3];
  const float* ent  = (const float*)d_in[4];
  const float* rele = (const float*)d_in[5];
  const float* in_w = (const float*)d_in[6];
  const float* in_b = (const float*)d_in[7];
  const float* q_w  = (const float*)d_in[8];
  const float* q_b  = (const float*)d_in[9];
  const float* k_w  = (const float*)d_in[10];
  const float* k_b  = (const float*)d_in[11];
  const float* v_w  = (const float*)d_in[12];
  const float* v_b  = (const float*)d_in[13];
  const float* w1   = (const float*)d_in[14];
  const float* b1   = (const float*)d_in[15];
  const float* w2   = (const float*)d_in[16];
  const float* b2   = (const float*)d_in[17];

  char* ws = (char*)d_ws;                                   // ~208 MiB total
  unsigned short* tem  = (unsigned short*)(ws + 0);         //  4,194,304
  float*          cur  = (float*)(ws + 4194304);            // 67,108,864
  unsigned short* enc  = (unsigned short*)(ws + 71303168);  // 33,554,432
  unsigned short* qb   = (unsigned short*)(ws + 104857600); // 33,554,432
  unsigned short* kb   = (unsigned short*)(ws + 138412032); // 33,554,432
  unsigned short* vtb  = (unsigned short*)(ws + 171966464); // 33,554,432
  float*          feat = (float*)(ws + 205520896);          //  1,048,576
  unsigned short* wT   = (unsigned short*)(ws + 206569472); //  1,966,080
  float* out = (float*)d_out;

  k_wprep<<<3840, 256, 0, stream>>>(in_w, q_w, k_w, v_w, wT);
  k_temporal<<<4096, 256, 0, stream>>>(tim, (unsigned int*)tem);
  k_inproj<<<1024, 256, 0, stream>>>(subj, obj, rel, ent, rele, wT, in_b, enc);

  for (int h = 0; h < 2; h++){
    for (int l = 0; l < 2; l++){
      int o = h * 2 + l;
      int lzero = (l == 0) ? 1 : 0;
      int hsave = (l == 1) ? h : -1;
      const unsigned short* wq = wT + 98304 + (size_t)(o * 3 + 0) * 73728;
      const unsigned short* wk = wT + 98304 + (size_t)(o * 3 + 1) * 73728;
      const unsigned short* wv = wT + 98304 + (size_t)(o * 3 + 2) * 73728;
      for (int c = 0; c < 2; c++){
        k_qkv<<<1024, 256, 0, stream>>>(enc, cur, tem, wq, wk, wv,
            q_b + o * 256, k_b + o * 256, v_b + o * 256, c, lzero, qb, kb, vtb);
        k_attn<<<256, 512, 0, stream>>>(qb, kb, vtb, enc, cur, tim, feat,
                                        c, lzero, hsave);
      }
    }
  }
  k_mlp<<<512, 256, 0, stream>>>(feat, w1, b1, w2, b2, out);
}

// Round 17
// 914.143 us; speedup vs baseline: 1.6996x; 1.0025x over previous
//
#include <hip/hip_runtime.h>
#include <math.h>
#include <stdint.h>

typedef __bf16 bf16x8 __attribute__((ext_vector_type(8)));
typedef float  f32x16 __attribute__((ext_vector_type(16)));
typedef unsigned int u32x4 __attribute__((ext_vector_type(4)));

static __device__ __forceinline__ f32x16 MFMA(bf16x8 a, bf16x8 b, f32x16 c){
  return __builtin_amdgcn_mfma_f32_32x32x16_bf16(a, b, c, 0, 0, 0);
}
static __device__ __forceinline__ unsigned short f2bf(float x){
  unsigned int u = __builtin_bit_cast(unsigned int, x);
  u += 0x7fffu + ((u >> 16) & 1u);   // RNE
  return (unsigned short)(u >> 16);
}
static __device__ __forceinline__ unsigned int pack2(float a, float b){
  return ((unsigned int)f2bf(b) << 16) | (unsigned int)f2bf(a);
}
static __device__ __forceinline__ bf16x8 ldfrag(const unsigned short* p){
  return __builtin_bit_cast(bf16x8, *(const uint4*)p);
}
// C-layout row for 32x32x16: row = (reg&3) + 8*(reg>>2) + 4*(lane>>5)
static __device__ __forceinline__ int rowmap(int reg, int lane){
  return (reg & 3) + 8 * (reg >> 2) + 4 * (lane >> 5);
}
// async global->LDS, 16 B per lane; LDS dest = wave-uniform base + lane*16
static __device__ __forceinline__ void gload_lds16(const void* g, void* l){
  __builtin_amdgcn_global_load_lds(
      reinterpret_cast<const __attribute__((address_space(1))) unsigned int*>(
          reinterpret_cast<uintptr_t>(g)),
      reinterpret_cast<__attribute__((address_space(3))) unsigned int*>(
          reinterpret_cast<uintptr_t>(l)),
      16, 0, 0);
}

// ------------------------------------------------ weight transpose+cast (once)
// in_w part: [col][384] (k_inproj unchanged). q/k/v parts: k-block-interleaved
// [k16][col][hi][8] so a GEMM wave's weight load is contiguous/coalesced.
__global__ __launch_bounds__(256) void k_wprep(const float* __restrict__ in_w,
    const float* __restrict__ q_w, const float* __restrict__ k_w,
    const float* __restrict__ v_w, unsigned short* __restrict__ wT){
  int idx = blockIdx.x * 256 + threadIdx.x;   // 983040 total
  float v;
  if (idx < 98304){
    int c = idx / 384, k = idx % 384;
    v = in_w[k * 256 + c];
  } else {
    int e = idx - 98304;
    int m = e / 73728, r = e % 73728;
    int k16 = r / 4096, rem = r % 4096;
    int c = rem / 16, kk = rem & 15;
    int k = k16 * 16 + kk;
    int p = m % 3, layer = m / 3;
    const float* src = (p == 0) ? q_w : (p == 1) ? k_w : v_w;
    v = src[(size_t)layer * 73728 + k * 256 + c];
  }
  wT[idx] = f2bf(v);
}

// ------------------------------------------------ temporal emb (bf16, masked)
__global__ __launch_bounds__(256) void k_temporal(const float* __restrict__ tim,
                                                  unsigned int* __restrict__ tem){
  int idx = blockIdx.x * 256 + threadIdx.x;   // 65536*16
  int i = idx & 15, m = idx >> 4;
  float t = tim[m];
  float np = (t > 0.0f) ? 1.0f : 0.0f;
  float dv = expf((float)(2 * i) * (-0.28782313662425576f));
  float arg = t * dv;
  tem[m * 16 + i] = pack2(sinf(arg) * np, cosf(arg) * np);
}

// ------------------------------------------------ input projection (MFMA)
__global__ __launch_bounds__(256, 2) void k_inproj(const int* __restrict__ subj,
    const int* __restrict__ obj, const int* __restrict__ rel,
    const float* __restrict__ ent, const float* __restrict__ rele,
    const unsigned short* __restrict__ inwT, const float* __restrict__ in_b,
    unsigned short* __restrict__ enc){
  __shared__ __align__(16) unsigned short A[64 * 392];  // reused as SB[64*264] after
  int t = threadIdx.x;
  int m0 = blockIdx.x * 64;
  { // gather 64 rows of concat(ent[s],ent[o],rel[r]) as bf16
    int r = t >> 2, c = t & 3;
    int m = m0 + r;
    const float4* s0 = (const float4*)(ent  + (size_t)subj[m] * 128 + c * 32);
    const float4* s1 = (const float4*)(ent  + (size_t)obj[m]  * 128 + c * 32);
    const float4* s2 = (const float4*)(rele + (size_t)rel[m]  * 128 + c * 32);
    unsigned int* dst = (unsigned int*)&A[r * 392];
#pragma unroll
    for (int j = 0; j < 8; j++){
      float4 f0 = s0[j], f1 = s1[j], f2 = s2[j];
      dst[c * 16 + 2 * j]           = pack2(f0.x, f0.y);
      dst[c * 16 + 2 * j + 1]       = pack2(f0.z, f0.w);
      dst[64 + c * 16 + 2 * j]      = pack2(f1.x, f1.y);
      dst[64 + c * 16 + 2 * j + 1]  = pack2(f1.z, f1.w);
      dst[128 + c * 16 + 2 * j]     = pack2(f2.x, f2.y);
      dst[128 + c * 16 + 2 * j + 1] = pack2(f2.z, f2.w);
    }
  }
  __syncthreads();
  int w = t >> 6, lane = t & 63;
  int lrow = lane & 31, khalf = (lane >> 5) * 8;
  int colA = (w * 2) * 32 + lrow, colB = colA + 32;
  f32x16 acc[2][2] = {};
  bf16x8 pb0 = ldfrag(&inwT[(size_t)colA * 384 + khalf]);
  bf16x8 pb1 = ldfrag(&inwT[(size_t)colB * 384 + khalf]);
  for (int ks = 0; ks < 24; ks++){
    int koff = ks * 16 + khalf;
    bf16x8 a0 = ldfrag(&A[lrow * 392 + koff]);
    bf16x8 a1 = ldfrag(&A[(32 + lrow) * 392 + koff]);
    bf16x8 b0 = pb0, b1 = pb1;
    if (ks < 23){
      pb0 = ldfrag(&inwT[(size_t)colA * 384 + koff + 16]);
      pb1 = ldfrag(&inwT[(size_t)colB * 384 + koff + 16]);
    }
    acc[0][0] = MFMA(a0, b0, acc[0][0]);
    acc[1][0] = MFMA(a1, b0, acc[1][0]);
    acc[0][1] = MFMA(a0, b1, acc[0][1]);
    acc[1][1] = MFMA(a1, b1, acc[1][1]);
  }
  float bs0 = in_b[colA], bs1 = in_b[colB];
  __syncthreads();            // A dead; reuse as SB[64][264]
#pragma unroll
  for (int rt = 0; rt < 2; rt++)
#pragma unroll
    for (int reg = 0; reg < 16; reg++){
      int row = rt * 32 + rowmap(reg, lane);
      A[row * 264 + colA] = f2bf(acc[rt][0][reg] + bs0);
      A[row * 264 + colB] = f2bf(acc[rt][1][reg] + bs1);
    }
  __syncthreads();
  {
    int r = t >> 2, s = t & 3;
    const uint4* src = (const uint4*)&A[r * 264 + s * 64];
    uint4* dst = (uint4*)(enc + ((size_t)m0 + r) * 256 + s * 64);
#pragma unroll
    for (int j = 0; j < 8; j++) dst[j] = src[j];
  }
}

// ------------------------------------------------ Q,K,V projections (MFMA)
// 52.5 KB LDS -> 3 blocks/CU. THREE separate GEMM passes (Q, K, V): 64-AGPR
// accumulator + depth-2 named-scalar weight prefetch (R15-verified; depth-4
// regressed). Coalesced k-block weights. Q -> qb interleaved
// [k16][query][hi][8]; K plain rows; V^T staged in 2 halves.

#define LOADA(KS, A0, A1)                                                        \
  do {                                                                           \
    if ((KS) < 16){                                                              \
      (A0) = ldfrag((const unsigned short*)(a0p + (((KS) * 32 + hi * 16) ^ aswz))); \
      (A1) = ldfrag((const unsigned short*)(a1p + (((KS) * 32 + hi * 16) ^ aswz))); \
    } else {                                                                     \
      int toff_ = ((KS) - 16) * 32 + hi * 16;                                    \
      (A0) = ldfrag((const unsigned short*)(a0p + 512 + (toff_ ^ (aswz & 48)))); \
      (A1) = ldfrag((const unsigned short*)(a1p + 512 + (toff_ ^ (aswz & 48)))); \
    }                                                                            \
  } while (0)

#define GEMM_PASS(WP, ACC)                                                       \
  do {                                                                           \
    bf16x8 w0A = ldfrag(&(WP)[colA * 16 + khalf]);                               \
    bf16x8 w0B = ldfrag(&(WP)[colB * 16 + khalf]);                               \
    bf16x8 w1A = ldfrag(&(WP)[4096 + colA * 16 + khalf]);                        \
    bf16x8 w1B = ldfrag(&(WP)[4096 + colB * 16 + khalf]);                        \
    _Pragma("unroll")                                                            \
    for (int k2 = 0; k2 < 9; k2++){                                              \
      int ks = 2 * k2;                                                           \
      {                                                                          \
        bf16x8 a0, a1; LOADA(ks, a0, a1);                                        \
        bf16x8 u0 = w0A, u1 = w0B;                                               \
        if (k2 < 8){                                                             \
          int kbase = (ks + 2) * 4096;                                           \
          w0A = ldfrag(&(WP)[kbase + colA * 16 + khalf]);                        \
          w0B = ldfrag(&(WP)[kbase + colB * 16 + khalf]);                        \
        }                                                                        \
        ACC[0][0] = MFMA(a0, u0, ACC[0][0]);                                     \
        ACC[1][0] = MFMA(a1, u0, ACC[1][0]);                                     \
        ACC[0][1] = MFMA(a0, u1, ACC[0][1]);                                     \
        ACC[1][1] = MFMA(a1, u1, ACC[1][1]);                                     \
      }                                                                          \
      {                                                                          \
        bf16x8 a0, a1; LOADA(ks + 1, a0, a1);                                    \
        bf16x8 u0 = w1A, u1 = w1B;                                               \
        if (k2 < 8){                                                             \
          int kbase = (ks + 3) * 4096;                                           \
          w1A = ldfrag(&(WP)[kbase + colA * 16 + khalf]);                        \
          w1B = ldfrag(&(WP)[kbase + colB * 16 + khalf]);                        \
        }                                                                        \
        ACC[0][0] = MFMA(a0, u0, ACC[0][0]);                                     \
        ACC[1][0] = MFMA(a1, u0, ACC[1][0]);                                     \
        ACC[0][1] = MFMA(a0, u1, ACC[0][1]);                                     \
        ACC[1][1] = MFMA(a1, u1, ACC[1][1]);                                     \
      }                                                                          \
    }                                                                            \
  } while (0)

// K store: plain [query][ch] rows (R12-verified)
#define STORE_RC(ACC, BIAS, OUT)                                                 \
  do {                                                                           \
    float bs0 = (BIAS)[colA], bs1 = (BIAS)[colB];                                \
    _Pragma("unroll")                                                            \
    for (int rt = 0; rt < 2; rt++){                                              \
      __syncthreads();                                                           \
      _Pragma("unroll")                                                          \
      for (int reg = 0; reg < 16; reg++){                                        \
        int row = rowmap(reg, lane);                                             \
        SB[row * 264 + colA] = f2bf(ACC[rt][0][reg] + bs0);                      \
        SB[row * 264 + colB] = f2bf(ACC[rt][1][reg] + bs1);                      \
      }                                                                          \
      __syncthreads();                                                           \
      int r = t >> 3, s = t & 7;                                                 \
      const uint4* src = (const uint4*)&SB[r * 264];                             \
      uint4* dst = (uint4*)((OUT) + ((size_t)nn * 256 + r0 + rt * 32 + r) * 256);\
      _Pragma("unroll")                                                          \
      for (int j = 0; j < 4; j++) dst[s * 4 + j] = src[s * 4 + j];               \
    }                                                                            \
  } while (0)

// Q store: k-block-interleaved [k16][query][hi][8] per nn (R15-verified)
#define STORE_Q(ACC, BIAS, OUT)                                                  \
  do {                                                                           \
    float bs0 = (BIAS)[colA], bs1 = (BIAS)[colB];                                \
    _Pragma("unroll")                                                            \
    for (int rt = 0; rt < 2; rt++){                                              \
      __syncthreads();                                                           \
      _Pragma("unroll")                                                          \
      for (int reg = 0; reg < 16; reg++){                                        \
        int row = rowmap(reg, lane);                                             \
        SB[row * 264 + colA] = f2bf(ACC[rt][0][reg] + bs0);                      \
        SB[row * 264 + colB] = f2bf(ACC[rt][1][reg] + bs1);                      \
      }                                                                          \
      __syncthreads();                                                           \
      int qr = t & 31, mb = t >> 5;                                              \
      _Pragma("unroll")                                                          \
      for (int it = 0; it < 4; it++){                                            \
        int m = it * 8 + mb;                                                     \
        uint4 val = *(const uint4*)&SB[qr * 264 + m * 8];                        \
        *(uint4*)((OUT) + (size_t)nn * 65536 + (m >> 1) * 4096 +                 \
                  (r0 + rt * 32 + qr) * 16 + (m & 1) * 8) = val;                 \
      }                                                                          \
    }                                                                            \
  } while (0)

__global__ __launch_bounds__(256, 3) void k_qkv(const unsigned short* __restrict__ enc,
    const float* __restrict__ cur, const unsigned short* __restrict__ tem,
    const unsigned short* __restrict__ wq, const unsigned short* __restrict__ wk,
    const unsigned short* __restrict__ wv, const float* __restrict__ bq,
    const float* __restrict__ bk, const float* __restrict__ bv,
    int chunk, int lzero,
    unsigned short* __restrict__ qb, unsigned short* __restrict__ kb,
    unsigned short* __restrict__ vtb){
  __shared__ __align__(16) unsigned short A[64 * 288];   // 36,864 B, swizzled 576-B rows
  __shared__ __align__(16) unsigned short SB[32 * 264];  // 16,896 B (= VT[128][66])
  char* Ab = (char*)A;
  int t = threadIdx.x;
  int nn = blockIdx.x >> 2;
  int n  = chunk * 256 + nn;
  int r0 = (blockIdx.x & 3) * 64;
  int w = t >> 6, lane = t & 63;
  int lrow = lane & 31, hi = lane >> 5, khalf = hi * 8;
  int colA = w * 64 + lrow, colB = colA + 32;

  { // gather 64 ci rows (enc | cur | zeros) + tem -> swizzled A
    int r = t >> 2, c4 = t & 3;
    int grow = r0 + r;
    int swz = (r & 7) << 4;
    char* dst = Ab + r * 576;
    if (grow < 128){
      const uint4* s4 = (const uint4*)(enc + ((size_t)n * 128 + grow) * 256 + c4 * 64);
#pragma unroll
      for (int j = 0; j < 8; j++)
        *(uint4*)(dst + ((c4 * 128 + j * 16) ^ swz)) = s4[j];
    } else if (!lzero){
      const float4* s4 = (const float4*)(cur + ((size_t)n * 128 + grow - 128) * 256 + c4 * 64);
#pragma unroll
      for (int j = 0; j < 8; j++){
        float4 fa = s4[2 * j], fb = s4[2 * j + 1];
        uint4 u = make_uint4(pack2(fa.x, fa.y), pack2(fa.z, fa.w),
                             pack2(fb.x, fb.y), pack2(fb.z, fb.w));
        *(uint4*)(dst + ((c4 * 128 + j * 16) ^ swz)) = u;
      }
    } else {
      uint4 z = make_uint4(0, 0, 0, 0);
#pragma unroll
      for (int j = 0; j < 8; j++)
        *(uint4*)(dst + ((c4 * 128 + j * 16) ^ swz)) = z;
    }
    int jr = (grow < 128) ? grow : grow - 128;
    *(uint4*)(dst + 512 + ((c4 * 16) ^ (swz & 48))) =
        *(const uint4*)(tem + ((size_t)n * 128 + jr) * 32 + c4 * 8);
  }
  __syncthreads();

  int aswz = (lrow & 7) << 4;            // (32+lrow)&7 == lrow&7
  const char* a0p = Ab + lrow * 576;
  const char* a1p = Ab + (32 + lrow) * 576;

  // ---- pass 1: Q (interleaved out) ----
  {
    f32x16 acc[2][2] = {};
    GEMM_PASS(wq, acc);
    STORE_Q(acc, bq, qb);
  }
  // ---- pass 2: K ----
  {
    f32x16 acc[2][2] = {};
    GEMM_PASS(wk, acc);
    STORE_RC(acc, bk, kb);
  }
  // ---- pass 3: V (transposed out via SB halves) ----
  {
    f32x16 acc[2][2] = {};
    GEMM_PASS(wv, acc);
    float bs0 = bv[colA], bs1 = bv[colB];
#pragma unroll
    for (int half = 0; half < 2; half++){
      __syncthreads();
      if ((w >> 1) == half){          // waves owning d in [half*128, half*128+128)
        int dA = colA & 127, dB = colB & 127;
#pragma unroll
        for (int rt = 0; rt < 2; rt++)
#pragma unroll
          for (int reg = 0; reg < 16; reg++){
            int kl = rt * 32 + rowmap(reg, lane);
            SB[dA * 66 + kl] = f2bf(acc[rt][0][reg] + bs0);
            SB[dB * 66 + kl] = f2bf(acc[rt][1][reg] + bs1);
          }
      }
      __syncthreads();
#pragma unroll
      for (int it = 0; it < 4; it++){
        int dl = it * 32 + (t >> 3), j = t & 7;
        const unsigned int* vs = (const unsigned int*)&SB[dl * 66];
        uint4 val = make_uint4(vs[j * 4], vs[j * 4 + 1], vs[j * 4 + 2], vs[j * 4 + 3]);
        *(uint4*)(vtb + ((size_t)nn * 256 + half * 128 + dl) * 256 + r0 + j * 8) = val;
      }
    }
  }
}

// ------------------------------------------------ attention, fused per-sequence
// 8 waves = 512 threads, one block per nn. Swapped QK^T, in-register max-free
// softmax, masked-tile skipping. K then V^T staged via global_load_lds with
// PRE-SWIZZLED SOURCE (rule #21: linear LDS dest, source column ^= (row&7),
// same involution as the reads). P in compact pw[5][8]. Coalesced qf.
// Folds k_savefeat (hsave>=0).
__global__ __launch_bounds__(512, 2) void k_attn(const unsigned short* __restrict__ qb,
    const unsigned short* __restrict__ kb, const unsigned short* __restrict__ vtb,
    unsigned short* __restrict__ enc, float* __restrict__ cur,
    const float* __restrict__ tim, float* __restrict__ feat,
    int chunk, int lzero, int hsave){
  __shared__ __align__(16) unsigned short KV[65536];   // 131072 B: [256 rows][512 B], byte ^= (row&7)<<4
  __shared__ float TS[128];
  char* KVb = (char*)KV;
  int t = threadIdx.x;
  int nn = blockIdx.x;
  int n  = chunk * 256 + nn;
  int w = t >> 6, lane = t & 63;
  int lrow = lane & 31, hi = lane >> 5;
  int hi4 = hi * 4;
  int q = w * 32 + lrow;
  const unsigned short* qn = qb  + (size_t)nn * 65536;
  const unsigned short* kn = kb  + (size_t)nn * 65536;
  const unsigned short* vn = vtb + (size_t)nn * 65536;

  if (t < 128) TS[t] = tim[(size_t)n * 128 + t];

  // ---- preload Q fragments (interleaved layout: coalesced) ----
  bf16x8 qf[16];
#pragma unroll
  for (int ks = 0; ks < 16; ks++)
    qf[ks] = ldfrag(&qn[ks * 4096 + q * 16 + hi * 8]);

  // ---- stage K -> LDS via global_load_lds (linear dest, pre-swizzled src) ----
#pragma unroll
  for (int it = 0; it < 16; it++){
    int rbase = w * 32 + it * 2;
    int row = rbase + hi;
    gload_lds16(kn + (size_t)row * 256 + ((lrow ^ (row & 7)) * 8),
                KVb + rbase * 512);
  }
  __syncthreads();

  // key-time==0 masks for keys 0..127 (lane-uniform words)
  unsigned long long mm0 = __ballot(TS[lane] == 0.0f);
  unsigned long long mm1 = __ballot(TS[lane + 64] == 0.0f);
  unsigned int tz32[4] = { (unsigned int)mm0, (unsigned int)(mm0 >> 32),
                           (unsigned int)mm1, (unsigned int)(mm1 >> 32) };

  bool top = (q < 128);
  int qcmp = q & 127;
  float sum = 0.0f;
  unsigned int pw[5][8];   // packed bf16 e-pairs; slot = kt<4 ? kt : 4

  // ---- QK^T (swapped: C[row=key][col=q]) + mask + exp + pack, per tile ----
#pragma unroll
  for (int kt = 0; kt < 8; kt++){
    const int slot = (kt < 4) ? kt : 4;
    bool need = top ? (kt <= w) : ((kt <= w - 4) || (kt == w));   // wave-uniform
    if (need){
      f32x16 s = {};
#pragma unroll
      for (int ks = 0; ks < 16; ks++){
        int row = kt * 32 + lrow;
        bf16x8 a = ldfrag((const unsigned short*)(KVb + row * 512 +
                          ((ks * 32 + hi * 16) ^ ((row & 7) << 4))));
        s = MFMA(a, qf[ks], s);
      }
#pragma unroll
      for (int j = 0; j < 8; j++){
        float e2[2];
#pragma unroll
        for (int u = 0; u < 2; u++){
          int r = 2 * j + u;
          int pat = (r & 3) + 8 * (r >> 2);
          int key = kt * 32 + pat + hi4;
          float sv = s[r] * 0.0625f;
          bool masked;
          if (kt < 4){
            bool tzb = (tz32[kt] >> (pat + hi4)) & 1;
            masked = (key >= qcmp) || tzb;
          } else {
            masked = top || (key != q);
          }
          float e = masked ? 0.0f : __expf(sv);
          sum += e;
          e2[u] = e;
        }
        pw[slot][j] = pack2(e2[0], e2[1]);
      }
    }
  }
  sum += __shfl_xor(sum, 32, 64);
  float rs = (sum > 0.0f) ? 1.0f / sum : 0.0f;
  bool am = (sum == 0.0f);   // all-masked row -> uniform 1/256 over ALL keys

  // ---- swap buffer to V^T[d][key] via global_load_lds (after QK) ----
  __syncthreads();           // all K reads done
#pragma unroll
  for (int it = 0; it < 16; it++){
    int rbase = w * 32 + it * 2;
    int row = rbase + hi;
    gload_lds16(vn + (size_t)row * 256 + ((lrow ^ (row & 7)) * 8),
                KVb + rbase * 512);
  }
  __syncthreads();

  // ---- PV: O^T[d][q] += V^T-frag x P-frag, masked tiles skipped ----
  f32x16 ov[8] = {};
#pragma unroll
  for (int kt = 0; kt < 8; kt++){
    const int slot = (kt < 4) ? kt : 4;
    bool need = top ? (kt <= w) : ((kt <= w - 4) || (kt == w));
    if (need){
      unsigned int s0 = __shfl_xor(pw[slot][0], 32, 64);
      unsigned int s1 = __shfl_xor(pw[slot][1], 32, 64);
      unsigned int s2 = __shfl_xor(pw[slot][2], 32, 64);
      unsigned int s3 = __shfl_xor(pw[slot][3], 32, 64);
      unsigned int s4 = __shfl_xor(pw[slot][4], 32, 64);
      unsigned int s5 = __shfl_xor(pw[slot][5], 32, 64);
      unsigned int s6 = __shfl_xor(pw[slot][6], 32, 64);
      unsigned int s7 = __shfl_xor(pw[slot][7], 32, 64);
      u32x4 fe = { hi ? s2 : pw[slot][0], hi ? s3 : pw[slot][1],
                   hi ? pw[slot][2] : s0, hi ? pw[slot][3] : s1 };
      u32x4 fo = { hi ? s6 : pw[slot][4], hi ? s7 : pw[slot][5],
                   hi ? pw[slot][6] : s4, hi ? pw[slot][7] : s5 };
      bf16x8 be = __builtin_bit_cast(bf16x8, fe);
      bf16x8 bo = __builtin_bit_cast(bf16x8, fo);
#pragma unroll
      for (int dt = 0; dt < 8; dt++){
        int row = dt * 32 + lrow;
        int swz = (row & 7) << 4;
        bf16x8 a0 = ldfrag((const unsigned short*)(KVb + row * 512 + ((kt * 64 + hi * 16) ^ swz)));
        bf16x8 a1 = ldfrag((const unsigned short*)(KVb + row * 512 + ((kt * 64 + 32 + hi * 16) ^ swz)));
        ov[dt] = MFMA(a0, be, ov[dt]);
        ov[dt] = MFMA(a1, bo, ov[dt]);
      }
    }
  }
  // normalize (deferred); am lanes get zero then the uniform pass below
#pragma unroll
  for (int dt = 0; dt < 8; dt++)
#pragma unroll
    for (int r = 0; r < 16; r++) ov[dt][r] *= rs;

  if (__ballot(am)){   // rare: wave 0 (q=0) structurally; lane-predicated uniform P
    float c = am ? 0.00390625f : 0.0f;
    unsigned int uwd = pack2(c, c);
    u32x4 fu = { uwd, uwd, uwd, uwd };
    bf16x8 bu = __builtin_bit_cast(bf16x8, fu);
#pragma unroll
    for (int s2i = 0; s2i < 16; s2i++){
#pragma unroll
      for (int dt = 0; dt < 8; dt++){
        int row = dt * 32 + lrow;
        bf16x8 a = ldfrag((const unsigned short*)(KVb + row * 512 +
                          ((s2i * 32 + hi * 16) ^ ((row & 7) << 4))));
        ov[dt] = MFMA(a, bu, ov[dt]);
      }
    }
  }

  // ---- epilogue: enc (q<128, bf16) then cur (q>=128, f32 tanh accumulate) ----
  __syncthreads();           // V^T reads done; KV reused for O staging
  if (w < 4){                // bf16 O[q][d], swizzled, lower 64 KB
#pragma unroll
    for (int dt = 0; dt < 8; dt++)
#pragma unroll
      for (int j = 0; j < 8; j++){
        int r = 2 * j;
        int pat = (r & 3) + 8 * (r >> 2);
        int d = dt * 32 + pat + hi4;
        *(unsigned int*)(KVb + q * 512 + ((d * 2) ^ ((q & 7) << 4))) =
            pack2(ov[dt][r], ov[dt][r + 1]);
      }
  }
  __syncthreads();
  {                          // coalesced store of enc
    int row = t >> 2;
    const char* src = KVb + row * 512;
    unsigned short* dst = enc + ((size_t)n * 128 + row) * 256;
    int swz = (row & 7) << 4;
#pragma unroll
    for (int jj = 0; jj < 8; jj++){
      int c = jj * 4 + (t & 3);
      uint4 v = *(const uint4*)(src + ((c * 16) ^ swz));
      *(uint4*)(dst + c * 8) = v;
    }
  }
  __syncthreads();
  if (w >= 4){               // f32 tanh values [qq][d], swizzled, full 128 KB
    int qq = q - 128;
    float tq = TS[qq];
#pragma unroll
    for (int dt = 0; dt < 8; dt++)
#pragma unroll
      for (int j = 0; j < 8; j++){
        int r = 2 * j;
        int pat = (r & 3) + 8 * (r >> 2);
        int d = dt * 32 + pat + hi4;
        float th0 = 0.0f, th1 = 0.0f;
        if (tq > 0.0f){
          th0 = 1.0f - 2.0f / (__expf(2.0f * ov[dt][r]) + 1.0f);
          th1 = 1.0f - 2.0f / (__expf(2.0f * ov[dt][r + 1]) + 1.0f);
        }
        float2 p2 = make_float2(th0, th1);
        *(float2*)(KVb + qq * 1024 + ((d * 4) ^ ((qq & 7) << 4))) = p2;
      }
  }
  __syncthreads();
  {                          // coalesced cur update (RMW unless lzero) + feat fold
    int row = t >> 2;
    int swz = (row & 7) << 4;
    const char* src = KVb + row * 1024;
    float* dst = cur + ((size_t)n * 128 + row) * 256;
#pragma unroll
    for (int jj = 0; jj < 16; jj++){
      int c = jj * 4 + (t & 3);
      float4 v = *(const float4*)(src + ((c * 16) ^ swz));
      if (!lzero){
        float4 o = *(const float4*)(dst + c * 4);
        v.x += o.x; v.y += o.y; v.z += o.z; v.w += o.w;
      }
      *(float4*)(dst + c * 4) = v;
      if (hsave >= 0 && row == 127)
        *(float4*)(feat + (size_t)n * 512 + hsave * 256 + c * 4) = v;
    }
  }
}

// ------------------------------------------------ output MLP head
__global__ __launch_bounds__(256) void k_mlp(const float* __restrict__ feat,
    const float* __restrict__ w1, const float* __restrict__ b1,
    const float* __restrict__ w2, const float* __restrict__ b2,
    float* __restrict__ out){
  __shared__ float F[512];
  __shared__ float red[4];
  int n = blockIdx.x, t = threadIdx.x;
  F[t]       = feat[(size_t)n * 512 + t];
  F[t + 256] = feat[(size_t)n * 512 + 256 + t];
  __syncthreads();
  float acc = 0.0f;
  for (int k4 = 0; k4 < 128; k4++){
    float b0v = w1[(k4 * 4 + 0) * 256 + t];
    float b1v = w1[(k4 * 4 + 1) * 256 + t];
    float b2v = w1[(k4 * 4 + 2) * 256 + t];
    float b3v = w1[(k4 * 4 + 3) * 256 + t];
    const float4 f = *(const float4*)&F[k4 * 4];
    acc = fmaf(f.x, b0v, fmaf(f.y, b1v, fmaf(f.z, b2v, fmaf(f.w, b3v, acc))));
  }
  acc += b1[t];
  float g = 0.5f * acc * (1.0f + erff(acc * 0.7071067811865475f));
  float part = g * w2[t];
#pragma unroll
  for (int mk = 1; mk < 64; mk <<= 1) part += __shfl_xor(part, mk, 64);
  if ((t & 63) == 0) red[t >> 6] = part;
  __syncthreads();
  if (t == 0) out[n] = red[0] + red[1] + red[2] + red[3] + b2[0];
}

// ------------------------------------------------ launch
extern "C" void kernel_launch(void* const* d_in, const int* in_sizes, int n_in,
                              void* d_out, int out_size, void* d_ws, size_t ws_size,
                              hipStream_t stream){
  const int*   subj = (const int*)  d_in[0];
  const int*   obj  = (const int*)  d_in[1];
  const int*   rel  = (const int*)  d_in[2];
  const float* tim  = (const float*)d_in[3];
  const float* ent  = (const float*)d_in[4];
  const float* rele = (const float*)d_in[5];
  const float* in_w = (const float*)d_in[6];
  const float* in_b = (const float*)d_in[7];
  const float* q_w  = (const float*)d_in[8];
  const float* q_b  = (const float*)d_in[9];
  const float* k_w  = (const float*)d_in[10];
  const float* k_b  = (const float*)d_in[11];
  const float* v_w  = (const float*)d_in[12];
  const float* v_b  = (const float*)d_in[13];
  const float* w1   = (const float*)d_in[14];
  const float* b1   = (const float*)d_in[15];
  const float* w2   = (const float*)d_in[16];
  const float* b2   = (const float*)d_in[17];

  char* ws = (char*)d_ws;                                   // ~208 MiB total
  unsigned short* tem  = (unsigned short*)(ws + 0);         //  4,194,304
  float*          cur  = (float*)(ws + 4194304);            // 67,108,864
  unsigned short* enc  = (unsigned short*)(ws + 71303168);  // 33,554,432
  unsigned short* qb   = (unsigned short*)(ws + 104857600); // 33,554,432
  unsigned short* kb   = (unsigned short*)(ws + 138412032); // 33,554,432
  unsigned short* vtb  = (unsigned short*)(ws + 171966464); // 33,554,432
  float*          feat = (float*)(ws + 205520896);          //  1,048,576
  unsigned short* wT   = (unsigned short*)(ws + 206569472); //  1,966,080
  float* out = (float*)d_out;

  k_wprep<<<3840, 256, 0, stream>>>(in_w, q_w, k_w, v_w, wT);
  k_temporal<<<4096, 256, 0, stream>>>(tim, (unsigned int*)tem);
  k_inproj<<<1024, 256, 0, stream>>>(subj, obj, rel, ent, rele, wT, in_b, enc);

  for (int h = 0; h < 2; h++){
    for (int l = 0; l < 2; l++){
      int o = h * 2 + l;
      int lzero = (l == 0) ? 1 : 0;
      int hsave = (l == 1) ? h : -1;
      const unsigned short* wq = wT + 98304 + (size_t)(o * 3 + 0) * 73728;
      const unsigned short* wk = wT + 98304 + (size_t)(o * 3 + 1) * 73728;
      const unsigned short* wv = wT + 98304 + (size_t)(o * 3 + 2) * 73728;
      for (int c = 0; c < 2; c++){
        k_qkv<<<1024, 256, 0, stream>>>(enc, cur, tem, wq, wk, wv,
            q_b + o * 256, k_b + o * 256, v_b + o * 256, c, lzero, qb, kb, vtb);
        k_attn<<<256, 512, 0, stream>>>(qb, kb, vtb, enc, cur, tim, feat,
                                        c, lzero, hsave);
      }
    }
  }
  k_mlp<<<512, 256, 0, stream>>>(feat, w1, b1, w2, b2, out);
}

// Round 18
// 905.652 us; speedup vs baseline: 1.7155x; 1.0094x over previous
//
#include <hip/hip_runtime.h>
#include <math.h>

typedef __bf16 bf16x8 __attribute__((ext_vector_type(8)));
typedef float  f32x16 __attribute__((ext_vector_type(16)));
typedef unsigned int u32x4 __attribute__((ext_vector_type(4)));

static __device__ __forceinline__ f32x16 MFMA(bf16x8 a, bf16x8 b, f32x16 c){
  return __builtin_amdgcn_mfma_f32_32x32x16_bf16(a, b, c, 0, 0, 0);
}
static __device__ __forceinline__ unsigned short f2bf(float x){
  unsigned int u = __builtin_bit_cast(unsigned int, x);
  u += 0x7fffu + ((u >> 16) & 1u);   // RNE
  return (unsigned short)(u >> 16);
}
static __device__ __forceinline__ unsigned int pack2(float a, float b){
  return ((unsigned int)f2bf(b) << 16) | (unsigned int)f2bf(a);
}
static __device__ __forceinline__ bf16x8 ldfrag(const unsigned short* p){
  return __builtin_bit_cast(bf16x8, *(const uint4*)p);
}
// C-layout row for 32x32x16: row = (reg&3) + 8*(reg>>2) + 4*(lane>>5)
static __device__ __forceinline__ int rowmap(int reg, int lane){
  return (reg & 3) + 8 * (reg >> 2) + 4 * (lane >> 5);
}

// ------------------------------------------------ weight transpose+cast (once)
// in_w part: [col][384] (k_inproj unchanged). q/k/v parts: k-block-interleaved
// [k16][col][hi][8] so a GEMM wave's weight load is contiguous/coalesced.
__global__ __launch_bounds__(256) void k_wprep(const float* __restrict__ in_w,
    const float* __restrict__ q_w, const float* __restrict__ k_w,
    const float* __restrict__ v_w, unsigned short* __restrict__ wT){
  int idx = blockIdx.x * 256 + threadIdx.x;   // 983040 total
  float v;
  if (idx < 98304){
    int c = idx / 384, k = idx % 384;
    v = in_w[k * 256 + c];
  } else {
    int e = idx - 98304;
    int m = e / 73728, r = e % 73728;
    int k16 = r / 4096, rem = r % 4096;
    int c = rem / 16, kk = rem & 15;
    int k = k16 * 16 + kk;
    int p = m % 3, layer = m / 3;
    const float* src = (p == 0) ? q_w : (p == 1) ? k_w : v_w;
    v = src[(size_t)layer * 73728 + k * 256 + c];
  }
  wT[idx] = f2bf(v);
}

// ------------------------------------------------ temporal emb (bf16, masked)
__global__ __launch_bounds__(256) void k_temporal(const float* __restrict__ tim,
                                                  unsigned int* __restrict__ tem){
  int idx = blockIdx.x * 256 + threadIdx.x;   // 65536*16
  int i = idx & 15, m = idx >> 4;
  float t = tim[m];
  float np = (t > 0.0f) ? 1.0f : 0.0f;
  float dv = expf((float)(2 * i) * (-0.28782313662425576f));
  float arg = t * dv;
  tem[m * 16 + i] = pack2(sinf(arg) * np, cosf(arg) * np);
}

// ------------------------------------------------ input projection (MFMA)
__global__ __launch_bounds__(256, 2) void k_inproj(const int* __restrict__ subj,
    const int* __restrict__ obj, const int* __restrict__ rel,
    const float* __restrict__ ent, const float* __restrict__ rele,
    const unsigned short* __restrict__ inwT, const float* __restrict__ in_b,
    unsigned short* __restrict__ enc){
  __shared__ __align__(16) unsigned short A[64 * 392];  // reused as SB[64*264] after
  int t = threadIdx.x;
  int m0 = blockIdx.x * 64;
  { // gather 64 rows of concat(ent[s],ent[o],rel[r]) as bf16
    int r = t >> 2, c = t & 3;
    int m = m0 + r;
    const float4* s0 = (const float4*)(ent  + (size_t)subj[m] * 128 + c * 32);
    const float4* s1 = (const float4*)(ent  + (size_t)obj[m]  * 128 + c * 32);
    const float4* s2 = (const float4*)(rele + (size_t)rel[m]  * 128 + c * 32);
    unsigned int* dst = (unsigned int*)&A[r * 392];
#pragma unroll
    for (int j = 0; j < 8; j++){
      float4 f0 = s0[j], f1 = s1[j], f2 = s2[j];
      dst[c * 16 + 2 * j]           = pack2(f0.x, f0.y);
      dst[c * 16 + 2 * j + 1]       = pack2(f0.z, f0.w);
      dst[64 + c * 16 + 2 * j]      = pack2(f1.x, f1.y);
      dst[64 + c * 16 + 2 * j + 1]  = pack2(f1.z, f1.w);
      dst[128 + c * 16 + 2 * j]     = pack2(f2.x, f2.y);
      dst[128 + c * 16 + 2 * j + 1] = pack2(f2.z, f2.w);
    }
  }
  __syncthreads();
  int w = t >> 6, lane = t & 63;
  int lrow = lane & 31, khalf = (lane >> 5) * 8;
  int colA = (w * 2) * 32 + lrow, colB = colA + 32;
  f32x16 acc[2][2] = {};
  bf16x8 pb0 = ldfrag(&inwT[(size_t)colA * 384 + khalf]);
  bf16x8 pb1 = ldfrag(&inwT[(size_t)colB * 384 + khalf]);
  for (int ks = 0; ks < 24; ks++){
    int koff = ks * 16 + khalf;
    bf16x8 a0 = ldfrag(&A[lrow * 392 + koff]);
    bf16x8 a1 = ldfrag(&A[(32 + lrow) * 392 + koff]);
    bf16x8 b0 = pb0, b1 = pb1;
    if (ks < 23){
      pb0 = ldfrag(&inwT[(size_t)colA * 384 + koff + 16]);
      pb1 = ldfrag(&inwT[(size_t)colB * 384 + koff + 16]);
    }
    acc[0][0] = MFMA(a0, b0, acc[0][0]);
    acc[1][0] = MFMA(a1, b0, acc[1][0]);
    acc[0][1] = MFMA(a0, b1, acc[0][1]);
    acc[1][1] = MFMA(a1, b1, acc[1][1]);
  }
  float bs0 = in_b[colA], bs1 = in_b[colB];
  __syncthreads();            // A dead; reuse as SB[64][264]
#pragma unroll
  for (int rt = 0; rt < 2; rt++)
#pragma unroll
    for (int reg = 0; reg < 16; reg++){
      int row = rt * 32 + rowmap(reg, lane);
      A[row * 264 + colA] = f2bf(acc[rt][0][reg] + bs0);
      A[row * 264 + colB] = f2bf(acc[rt][1][reg] + bs1);
    }
  __syncthreads();
  {
    int r = t >> 2, s = t & 3;
    const uint4* src = (const uint4*)&A[r * 264 + s * 64];
    uint4* dst = (uint4*)(enc + ((size_t)m0 + r) * 256 + s * 64);
#pragma unroll
    for (int j = 0; j < 8; j++) dst[j] = src[j];
  }
}

// ------------------------------------------------ Q,K,V projections (MFMA)
// 52.5 KB LDS -> 3 blocks/CU. THREE separate GEMM passes (Q, K, V): 64-AGPR
// accumulator + depth-2 named-scalar weight prefetch (verified best; depth-4
// regressed). Coalesced k-block weights. Q -> qb interleaved
// [k16][query][hi][8]; K plain rows; V^T staged in 2 halves.

#define LOADA(KS, A0, A1)                                                        \
  do {                                                                           \
    if ((KS) < 16){                                                              \
      (A0) = ldfrag((const unsigned short*)(a0p + (((KS) * 32 + hi * 16) ^ aswz))); \
      (A1) = ldfrag((const unsigned short*)(a1p + (((KS) * 32 + hi * 16) ^ aswz))); \
    } else {                                                                     \
      int toff_ = ((KS) - 16) * 32 + hi * 16;                                    \
      (A0) = ldfrag((const unsigned short*)(a0p + 512 + (toff_ ^ (aswz & 48)))); \
      (A1) = ldfrag((const unsigned short*)(a1p + 512 + (toff_ ^ (aswz & 48)))); \
    }                                                                            \
  } while (0)

#define GEMM_PASS(WP, ACC)                                                       \
  do {                                                                           \
    bf16x8 w0A = ldfrag(&(WP)[colA * 16 + khalf]);                               \
    bf16x8 w0B = ldfrag(&(WP)[colB * 16 + khalf]);                               \
    bf16x8 w1A = ldfrag(&(WP)[4096 + colA * 16 + khalf]);                        \
    bf16x8 w1B = ldfrag(&(WP)[4096 + colB * 16 + khalf]);                        \
    _Pragma("unroll")                                                            \
    for (int k2 = 0; k2 < 9; k2++){                                              \
      int ks = 2 * k2;                                                           \
      {                                                                          \
        bf16x8 a0, a1; LOADA(ks, a0, a1);                                        \
        bf16x8 u0 = w0A, u1 = w0B;                                               \
        if (k2 < 8){                                                             \
          int kbase = (ks + 2) * 4096;                                           \
          w0A = ldfrag(&(WP)[kbase + colA * 16 + khalf]);                        \
          w0B = ldfrag(&(WP)[kbase + colB * 16 + khalf]);                        \
        }                                                                        \
        ACC[0][0] = MFMA(a0, u0, ACC[0][0]);                                     \
        ACC[1][0] = MFMA(a1, u0, ACC[1][0]);                                     \
        ACC[0][1] = MFMA(a0, u1, ACC[0][1]);                                     \
        ACC[1][1] = MFMA(a1, u1, ACC[1][1]);                                     \
      }                                                                          \
      {                                                                          \
        bf16x8 a0, a1; LOADA(ks + 1, a0, a1);                                    \
        bf16x8 u0 = w1A, u1 = w1B;                                               \
        if (k2 < 8){                                                             \
          int kbase = (ks + 3) * 4096;                                           \
          w1A = ldfrag(&(WP)[kbase + colA * 16 + khalf]);                        \
          w1B = ldfrag(&(WP)[kbase + colB * 16 + khalf]);                        \
        }                                                                        \
        ACC[0][0] = MFMA(a0, u0, ACC[0][0]);                                     \
        ACC[1][0] = MFMA(a1, u0, ACC[1][0]);                                     \
        ACC[0][1] = MFMA(a0, u1, ACC[0][1]);                                     \
        ACC[1][1] = MFMA(a1, u1, ACC[1][1]);                                     \
      }                                                                          \
    }                                                                            \
  } while (0)

// K store: plain [query][ch] rows (R12-verified)
#define STORE_RC(ACC, BIAS, OUT)                                                 \
  do {                                                                           \
    float bs0 = (BIAS)[colA], bs1 = (BIAS)[colB];                                \
    _Pragma("unroll")                                                            \
    for (int rt = 0; rt < 2; rt++){                                              \
      __syncthreads();                                                           \
      _Pragma("unroll")                                                          \
      for (int reg = 0; reg < 16; reg++){                                        \
        int row = rowmap(reg, lane);                                             \
        SB[row * 264 + colA] = f2bf(ACC[rt][0][reg] + bs0);                      \
        SB[row * 264 + colB] = f2bf(ACC[rt][1][reg] + bs1);                      \
      }                                                                          \
      __syncthreads();                                                           \
      int r = t >> 3, s = t & 7;                                                 \
      const uint4* src = (const uint4*)&SB[r * 264];                             \
      uint4* dst = (uint4*)((OUT) + ((size_t)nn * 256 + r0 + rt * 32 + r) * 256);\
      _Pragma("unroll")                                                          \
      for (int j = 0; j < 4; j++) dst[s * 4 + j] = src[s * 4 + j];               \
    }                                                                            \
  } while (0)

// Q store: k-block-interleaved [k16][query][hi][8] per nn (R15-verified)
#define STORE_Q(ACC, BIAS, OUT)                                                  \
  do {                                                                           \
    float bs0 = (BIAS)[colA], bs1 = (BIAS)[colB];                                \
    _Pragma("unroll")                                                            \
    for (int rt = 0; rt < 2; rt++){                                              \
      __syncthreads();                                                           \
      _Pragma("unroll")                                                          \
      for (int reg = 0; reg < 16; reg++){                                        \
        int row = rowmap(reg, lane);                                             \
        SB[row * 264 + colA] = f2bf(ACC[rt][0][reg] + bs0);                      \
        SB[row * 264 + colB] = f2bf(ACC[rt][1][reg] + bs1);                      \
      }                                                                          \
      __syncthreads();                                                           \
      int qr = t & 31, mb = t >> 5;                                              \
      _Pragma("unroll")                                                          \
      for (int it = 0; it < 4; it++){                                            \
        int m = it * 8 + mb;                                                     \
        uint4 val = *(const uint4*)&SB[qr * 264 + m * 8];                        \
        *(uint4*)((OUT) + (size_t)nn * 65536 + (m >> 1) * 4096 +                 \
                  (r0 + rt * 32 + qr) * 16 + (m & 1) * 8) = val;                 \
      }                                                                          \
    }                                                                            \
  } while (0)

__global__ __launch_bounds__(256, 3) void k_qkv(const unsigned short* __restrict__ enc,
    const float* __restrict__ cur, const unsigned short* __restrict__ tem,
    const unsigned short* __restrict__ wq, const unsigned short* __restrict__ wk,
    const unsigned short* __restrict__ wv, const float* __restrict__ bq,
    const float* __restrict__ bk, const float* __restrict__ bv,
    int chunk, int lzero,
    unsigned short* __restrict__ qb, unsigned short* __restrict__ kb,
    unsigned short* __restrict__ vtb){
  __shared__ __align__(16) unsigned short A[64 * 288];   // 36,864 B, swizzled 576-B rows
  __shared__ __align__(16) unsigned short SB[32 * 264];  // 16,896 B (= VT[128][66])
  char* Ab = (char*)A;
  int t = threadIdx.x;
  int nn = blockIdx.x >> 2;
  int n  = chunk * 256 + nn;
  int r0 = (blockIdx.x & 3) * 64;
  int w = t >> 6, lane = t & 63;
  int lrow = lane & 31, hi = lane >> 5, khalf = hi * 8;
  int colA = w * 64 + lrow, colB = colA + 32;

  { // gather 64 ci rows (enc | cur | zeros) + tem -> swizzled A
    int r = t >> 2, c4 = t & 3;
    int grow = r0 + r;
    int swz = (r & 7) << 4;
    char* dst = Ab + r * 576;
    if (grow < 128){
      const uint4* s4 = (const uint4*)(enc + ((size_t)n * 128 + grow) * 256 + c4 * 64);
#pragma unroll
      for (int j = 0; j < 8; j++)
        *(uint4*)(dst + ((c4 * 128 + j * 16) ^ swz)) = s4[j];
    } else if (!lzero){
      const float4* s4 = (const float4*)(cur + ((size_t)n * 128 + grow - 128) * 256 + c4 * 64);
#pragma unroll
      for (int j = 0; j < 8; j++){
        float4 fa = s4[2 * j], fb = s4[2 * j + 1];
        uint4 u = make_uint4(pack2(fa.x, fa.y), pack2(fa.z, fa.w),
                             pack2(fb.x, fb.y), pack2(fb.z, fb.w));
        *(uint4*)(dst + ((c4 * 128 + j * 16) ^ swz)) = u;
      }
    } else {
      uint4 z = make_uint4(0, 0, 0, 0);
#pragma unroll
      for (int j = 0; j < 8; j++)
        *(uint4*)(dst + ((c4 * 128 + j * 16) ^ swz)) = z;
    }
    int jr = (grow < 128) ? grow : grow - 128;
    *(uint4*)(dst + 512 + ((c4 * 16) ^ (swz & 48))) =
        *(const uint4*)(tem + ((size_t)n * 128 + jr) * 32 + c4 * 8);
  }
  __syncthreads();

  int aswz = (lrow & 7) << 4;            // (32+lrow)&7 == lrow&7
  const char* a0p = Ab + lrow * 576;
  const char* a1p = Ab + (32 + lrow) * 576;

  // ---- pass 1: Q (interleaved out) ----
  {
    f32x16 acc[2][2] = {};
    GEMM_PASS(wq, acc);
    STORE_Q(acc, bq, qb);
  }
  // ---- pass 2: K ----
  {
    f32x16 acc[2][2] = {};
    GEMM_PASS(wk, acc);
    STORE_RC(acc, bk, kb);
  }
  // ---- pass 3: V (transposed out via SB halves) ----
  {
    f32x16 acc[2][2] = {};
    GEMM_PASS(wv, acc);
    float bs0 = bv[colA], bs1 = bv[colB];
#pragma unroll
    for (int half = 0; half < 2; half++){
      __syncthreads();
      if ((w >> 1) == half){          // waves owning d in [half*128, half*128+128)
        int dA = colA & 127, dB = colB & 127;
#pragma unroll
        for (int rt = 0; rt < 2; rt++)
#pragma unroll
          for (int reg = 0; reg < 16; reg++){
            int kl = rt * 32 + rowmap(reg, lane);
            SB[dA * 66 + kl] = f2bf(acc[rt][0][reg] + bs0);
            SB[dB * 66 + kl] = f2bf(acc[rt][1][reg] + bs1);
          }
      }
      __syncthreads();
#pragma unroll
      for (int it = 0; it < 4; it++){
        int dl = it * 32 + (t >> 3), j = t & 7;
        const unsigned int* vs = (const unsigned int*)&SB[dl * 66];
        uint4 val = make_uint4(vs[j * 4], vs[j * 4 + 1], vs[j * 4 + 2], vs[j * 4 + 3]);
        *(uint4*)(vtb + ((size_t)nn * 256 + half * 128 + dl) * 256 + r0 + j * 8) = val;
      }
    }
  }
}

// ------------------------------------------------ attention, fused per-sequence
// 8 waves = 512 threads, one block per nn. Swapped QK^T, in-register max-free
// softmax, masked-tile skipping. K then V^T staged (reg-staged; gload_lds
// regressed in R17) in one XOR-swizzled 128 KB LDS buffer. V loaded AFTER QK
// (no 64-reg park); P in compact pw[5][8]. Coalesced qf (interleaved qb).
// Folds k_savefeat (hsave>=0).
__global__ __launch_bounds__(512, 2) void k_attn(const unsigned short* __restrict__ qb,
    const unsigned short* __restrict__ kb, const unsigned short* __restrict__ vtb,
    unsigned short* __restrict__ enc, float* __restrict__ cur,
    const float* __restrict__ tim, float* __restrict__ feat,
    int chunk, int lzero, int hsave){
  __shared__ __align__(16) unsigned short KV[65536];   // 131072 B: [256 rows][512 B], byte ^= (row&7)<<4
  __shared__ float TS[128];
  char* KVb = (char*)KV;
  int t = threadIdx.x;
  int nn = blockIdx.x;
  int n  = chunk * 256 + nn;
  int w = t >> 6, lane = t & 63;
  int lrow = lane & 31, hi = lane >> 5;
  int hi4 = hi * 4;
  int q = w * 32 + lrow;
  const unsigned short* qn = qb  + (size_t)nn * 65536;
  const unsigned short* kn = kb  + (size_t)nn * 65536;
  const unsigned short* vn = vtb + (size_t)nn * 65536;

  if (t < 128) TS[t] = tim[(size_t)n * 128 + t];

  // ---- preload Q fragments (interleaved layout: coalesced) ----
  bf16x8 qf[16];
#pragma unroll
  for (int ks = 0; ks < 16; ks++)
    qf[ks] = ldfrag(&qn[ks * 4096 + q * 16 + hi * 8]);

  // ---- stage K[key][d] -> LDS, swizzled; wave w owns rows [32w, 32w+32) ----
#pragma unroll
  for (int it = 0; it < 16; it++){
    int row = w * 32 + it * 2 + hi;
    uint4 v = *(const uint4*)(kn + (size_t)row * 256 + lrow * 8);
    *(uint4*)(KVb + row * 512 + ((lrow * 16) ^ ((row & 7) << 4))) = v;
  }
  __syncthreads();

  // key-time==0 masks for keys 0..127 (lane-uniform words)
  unsigned long long mm0 = __ballot(TS[lane] == 0.0f);
  unsigned long long mm1 = __ballot(TS[lane + 64] == 0.0f);
  unsigned int tz32[4] = { (unsigned int)mm0, (unsigned int)(mm0 >> 32),
                           (unsigned int)mm1, (unsigned int)(mm1 >> 32) };

  bool top = (q < 128);
  int qcmp = q & 127;
  float sum = 0.0f;
  unsigned int pw[5][8];   // packed bf16 e-pairs; slot = kt<4 ? kt : 4

  // ---- QK^T (swapped: C[row=key][col=q]) + mask + exp + pack, per tile ----
#pragma unroll
  for (int kt = 0; kt < 8; kt++){
    const int slot = (kt < 4) ? kt : 4;
    bool need = top ? (kt <= w) : ((kt <= w - 4) || (kt == w));   // wave-uniform
    if (need){
      f32x16 s = {};
#pragma unroll
      for (int ks = 0; ks < 16; ks++){
        int row = kt * 32 + lrow;
        bf16x8 a = ldfrag((const unsigned short*)(KVb + row * 512 +
                          ((ks * 32 + hi * 16) ^ ((row & 7) << 4))));
        s = MFMA(a, qf[ks], s);
      }
#pragma unroll
      for (int j = 0; j < 8; j++){
        float e2[2];
#pragma unroll
        for (int u = 0; u < 2; u++){
          int r = 2 * j + u;
          int pat = (r & 3) + 8 * (r >> 2);
          int key = kt * 32 + pat + hi4;
          float sv = s[r] * 0.0625f;
          bool masked;
          if (kt < 4){
            bool tzb = (tz32[kt] >> (pat + hi4)) & 1;
            masked = (key >= qcmp) || tzb;
          } else {
            masked = top || (key != q);
          }
          float e = masked ? 0.0f : __expf(sv);
          sum += e;
          e2[u] = e;
        }
        pw[slot][j] = pack2(e2[0], e2[1]);
      }
    }
  }
  sum += __shfl_xor(sum, 32, 64);
  float rs = (sum > 0.0f) ? 1.0f / sum : 0.0f;
  bool am = (sum == 0.0f);   // all-masked row -> uniform 1/256 over ALL keys

  // ---- swap buffer to V^T[d][key]: load AFTER QK (qf dead; no reg park) ----
  __syncthreads();           // all K reads done
#pragma unroll
  for (int it = 0; it < 16; it++){
    int row = w * 32 + it * 2 + hi;
    uint4 v = *(const uint4*)(vn + (size_t)row * 256 + lrow * 8);
    *(uint4*)(KVb + row * 512 + ((lrow * 16) ^ ((row & 7) << 4))) = v;
  }
  __syncthreads();

  // ---- PV: O^T[d][q] += V^T-frag x P-frag, masked tiles skipped ----
  f32x16 ov[8] = {};
#pragma unroll
  for (int kt = 0; kt < 8; kt++){
    const int slot = (kt < 4) ? kt : 4;
    bool need = top ? (kt <= w) : ((kt <= w - 4) || (kt == w));
    if (need){
      unsigned int s0 = __shfl_xor(pw[slot][0], 32, 64);
      unsigned int s1 = __shfl_xor(pw[slot][1], 32, 64);
      unsigned int s2 = __shfl_xor(pw[slot][2], 32, 64);
      unsigned int s3 = __shfl_xor(pw[slot][3], 32, 64);
      unsigned int s4 = __shfl_xor(pw[slot][4], 32, 64);
      unsigned int s5 = __shfl_xor(pw[slot][5], 32, 64);
      unsigned int s6 = __shfl_xor(pw[slot][6], 32, 64);
      unsigned int s7 = __shfl_xor(pw[slot][7], 32, 64);
      u32x4 fe = { hi ? s2 : pw[slot][0], hi ? s3 : pw[slot][1],
                   hi ? pw[slot][2] : s0, hi ? pw[slot][3] : s1 };
      u32x4 fo = { hi ? s6 : pw[slot][4], hi ? s7 : pw[slot][5],
                   hi ? pw[slot][6] : s4, hi ? pw[slot][7] : s5 };
      bf16x8 be = __builtin_bit_cast(bf16x8, fe);
      bf16x8 bo = __builtin_bit_cast(bf16x8, fo);
#pragma unroll
      for (int dt = 0; dt < 8; dt++){
        int row = dt * 32 + lrow;
        int swz = (row & 7) << 4;
        bf16x8 a0 = ldfrag((const unsigned short*)(KVb + row * 512 + ((kt * 64 + hi * 16) ^ swz)));
        bf16x8 a1 = ldfrag((const unsigned short*)(KVb + row * 512 + ((kt * 64 + 32 + hi * 16) ^ swz)));
        ov[dt] = MFMA(a0, be, ov[dt]);
        ov[dt] = MFMA(a1, bo, ov[dt]);
      }
    }
  }
  // normalize (deferred); am lanes get zero then the uniform pass below
#pragma unroll
  for (int dt = 0; dt < 8; dt++)
#pragma unroll
    for (int r = 0; r < 16; r++) ov[dt][r] *= rs;

  if (__ballot(am)){   // rare: wave 0 (q=0) structurally; lane-predicated uniform P
    float c = am ? 0.00390625f : 0.0f;
    unsigned int uwd = pack2(c, c);
    u32x4 fu = { uwd, uwd, uwd, uwd };
    bf16x8 bu = __builtin_bit_cast(bf16x8, fu);
#pragma unroll
    for (int s2i = 0; s2i < 16; s2i++){
#pragma unroll
      for (int dt = 0; dt < 8; dt++){
        int row = dt * 32 + lrow;
        bf16x8 a = ldfrag((const unsigned short*)(KVb + row * 512 +
                          ((s2i * 32 + hi * 16) ^ ((row & 7) << 4))));
        ov[dt] = MFMA(a, bu, ov[dt]);
      }
    }
  }

  // ---- epilogue: enc (q<128, bf16) then cur (q>=128, f32 tanh accumulate) ----
  __syncthreads();           // V^T reads done; KV reused for O staging
  if (w < 4){                // bf16 O[q][d], swizzled, lower 64 KB
#pragma unroll
    for (int dt = 0; dt < 8; dt++)
#pragma unroll
      for (int j = 0; j < 8; j++){
        int r = 2 * j;
        int pat = (r & 3) + 8 * (r >> 2);
        int d = dt * 32 + pat + hi4;
        *(unsigned int*)(KVb + q * 512 + ((d * 2) ^ ((q & 7) << 4))) =
            pack2(ov[dt][r], ov[dt][r + 1]);
      }
  }
  __syncthreads();
  {                          // coalesced store of enc
    int row = t >> 2;
    const char* src = KVb + row * 512;
    unsigned short* dst = enc + ((size_t)n * 128 + row) * 256;
    int swz = (row & 7) << 4;
#pragma unroll
    for (int jj = 0; jj < 8; jj++){
      int c = jj * 4 + (t & 3);
      uint4 v = *(const uint4*)(src + ((c * 16) ^ swz));
      *(uint4*)(dst + c * 8) = v;
    }
  }
  __syncthreads();
  if (w >= 4){               // f32 tanh values [qq][d], swizzled, full 128 KB
    int qq = q - 128;
    float tq = TS[qq];
#pragma unroll
    for (int dt = 0; dt < 8; dt++)
#pragma unroll
      for (int j = 0; j < 8; j++){
        int r = 2 * j;
        int pat = (r & 3) + 8 * (r >> 2);
        int d = dt * 32 + pat + hi4;
        float th0 = 0.0f, th1 = 0.0f;
        if (tq > 0.0f){
          th0 = 1.0f - 2.0f / (__expf(2.0f * ov[dt][r]) + 1.0f);
          th1 = 1.0f - 2.0f / (__expf(2.0f * ov[dt][r + 1]) + 1.0f);
        }
        float2 p2 = make_float2(th0, th1);
        *(float2*)(KVb + qq * 1024 + ((d * 4) ^ ((qq & 7) << 4))) = p2;
      }
  }
  __syncthreads();
  {                          // coalesced cur update (RMW unless lzero) + feat fold
    int row = t >> 2;
    int swz = (row & 7) << 4;
    const char* src = KVb + row * 1024;
    float* dst = cur + ((size_t)n * 128 + row) * 256;
#pragma unroll
    for (int jj = 0; jj < 16; jj++){
      int c = jj * 4 + (t & 3);
      float4 v = *(const float4*)(src + ((c * 16) ^ swz));
      if (!lzero){
        float4 o = *(const float4*)(dst + c * 4);
        v.x += o.x; v.y += o.y; v.z += o.z; v.w += o.w;
      }
      *(float4*)(dst + c * 4) = v;
      if (hsave >= 0 && row == 127)
        *(float4*)(feat + (size_t)n * 512 + hsave * 256 + c * 4) = v;
    }
  }
}

// ------------------------------------------------ output MLP head
__global__ __launch_bounds__(256) void k_mlp(const float* __restrict__ feat,
    const float* __restrict__ w1, const float* __restrict__ b1,
    const float* __restrict__ w2, const float* __restrict__ b2,
    float* __restrict__ out){
  __shared__ float F[512];
  __shared__ float red[4];
  int n = blockIdx.x, t = threadIdx.x;
  F[t]       = feat[(size_t)n * 512 + t];
  F[t + 256] = feat[(size_t)n * 512 + 256 + t];
  __syncthreads();
  float acc = 0.0f;
  for (int k4 = 0; k4 < 128; k4++){
    float b0v = w1[(k4 * 4 + 0) * 256 + t];
    float b1v = w1[(k4 * 4 + 1) * 256 + t];
    float b2v = w1[(k4 * 4 + 2) * 256 + t];
    float b3v = w1[(k4 * 4 + 3) * 256 + t];
    const float4 f = *(const float4*)&F[k4 * 4];
    acc = fmaf(f.x, b0v, fmaf(f.y, b1v, fmaf(f.z, b2v, fmaf(f.w, b3v, acc))));
  }
  acc += b1[t];
  float g = 0.5f * acc * (1.0f + erff(acc * 0.7071067811865475f));
  float part = g * w2[t];
#pragma unroll
  for (int mk = 1; mk < 64; mk <<= 1) part += __shfl_xor(part, mk, 64);
  if ((t & 63) == 0) red[t >> 6] = part;
  __syncthreads();
  if (t == 0) out[n] = red[0] + red[1] + red[2] + red[3] + b2[0];
}

// ------------------------------------------------ launch
extern "C" void kernel_launch(void* const* d_in, const int* in_sizes, int n_in,
                              void* d_out, int out_size, void* d_ws, size_t ws_size,
                              hipStream_t stream){
  const int*   subj = (const int*)  d_in[0];
  const int*   obj  = (const int*)  d_in[1];
  const int*   rel  = (const int*)  d_in[2];
  const float* tim  = (const float*)d_in[3];
  const float* ent  = (const float*)d_in[4];
  const float* rele = (const float*)d_in[5];
  const float* in_w = (const float*)d_in[6];
  const float* in_b = (const float*)d_in[7];
  const float* q_w  = (const float*)d_in[8];
  const float* q_b  = (const float*)d_in[9];
  const float* k_w  = (const float*)d_in[10];
  const float* k_b  = (const float*)d_in[11];
  const float* v_w  = (const float*)d_in[12];
  const float* v_b  = (const float*)d_in[13];
  const float* w1   = (const float*)d_in[14];
  const float* b1   = (const float*)d_in[15];
  const float* w2   = (const float*)d_in[16];
  const float* b2   = (const float*)d_in[17];

  char* ws = (char*)d_ws;                                   // ~208 MiB total
  unsigned short* tem  = (unsigned short*)(ws + 0);         //  4,194,304
  float*          cur  = (float*)(ws + 4194304);            // 67,108,864
  unsigned short* enc  = (unsigned short*)(ws + 71303168);  // 33,554,432
  unsigned short* qb   = (unsigned short*)(ws + 104857600); // 33,554,432
  unsigned short* kb   = (unsigned short*)(ws + 138412032); // 33,554,432
  unsigned short* vtb  = (unsigned short*)(ws + 171966464); // 33,554,432
  float*          feat = (float*)(ws + 205520896);          //  1,048,576
  unsigned short* wT   = (unsigned short*)(ws + 206569472); //  1,966,080
  float* out = (float*)d_out;

  k_wprep<<<3840, 256, 0, stream>>>(in_w, q_w, k_w, v_w, wT);
  k_temporal<<<4096, 256, 0, stream>>>(tim, (unsigned int*)tem);
  k_inproj<<<1024, 256, 0, stream>>>(subj, obj, rel, ent, rele, wT, in_b, enc);

  for (int h = 0; h < 2; h++){
    for (int l = 0; l < 2; l++){
      int o = h * 2 + l;
      int lzero = (l == 0) ? 1 : 0;
      int hsave = (l == 1) ? h : -1;
      const unsigned short* wq = wT + 98304 + (size_t)(o * 3 + 0) * 73728;
      const unsigned short* wk = wT + 98304 + (size_t)(o * 3 + 1) * 73728;
      const unsigned short* wv = wT + 98304 + (size_t)(o * 3 + 2) * 73728;
      for (int c = 0; c < 2; c++){
        k_qkv<<<1024, 256, 0, stream>>>(enc, cur, tem, wq, wk, wv,
            q_b + o * 256, k_b + o * 256, v_b + o * 256, c, lzero, qb, kb, vtb);
        k_attn<<<256, 512, 0, stream>>>(qb, kb, vtb, enc, cur, tim, feat,
                                        c, lzero, hsave);
      }
    }
  }
  k_mlp<<<512, 256, 0, stream>>>(feat, w1, b1, w2, b2, out);
}